// Round 7
// baseline (348.127 us; speedup 1.0000x reference)
//
#include <hip/hip_runtime.h>

// Attention with policy-softmax, MI355X (gfx950).
// Shapes: B=16, N=1024, C=768, H=12, hd=64.
// R12: GEMMs rebuilt at 256x256/BK=64 (m201-class geometry). R10/R11 proved
// the 128^2 2-barrier structure is the ceiling (~400 TF) regardless of
// pipeline depth: MFMA ~19.4cy/SIMD and LDS ~12cy/b128 both idle ~55% in
// barrier lockstep. 256^2: 8 waves (512thr), per-wave 128x64 -> 24 ds_read
// per 64 MFMA (-25%/FLOP), ONE barrier per K-tile (stage issued AFTER the
// barrier targets only the non-read buffer -> no WAR), XOR-swizzled LDS
// (128B rows would be 16-way conflicts unswizzled; pre-swizzled global
// source + swizzled read, rule #21), vmcnt(0) at top drains tile-old loads
// (free). LDS 128KB, 1 block/CU. attn unchanged from R9b (proven).

#define NB 16
#define NN 1024
#define NC 768
#define NH 12
#define HD 64
#define NM (NB*NN)      // 16384
#define QKVC (3*NC)     // 2304
#define QSCALE 0.18033688011112042f   // 0.125 * log2(e)
#define PSTR 68         // attn sP row stride in f16 (136B)

typedef _Float16 f16;
typedef _Float16 f16x8 __attribute__((ext_vector_type(8)));
typedef _Float16 f16x4 __attribute__((ext_vector_type(4)));
typedef __fp16 fp16x2 __attribute__((ext_vector_type(2)));   // cvt_pkrtz native type
typedef float f32x4 __attribute__((ext_vector_type(4)));

#if __has_builtin(__builtin_amdgcn_exp2f)
#define EXP2(x) __builtin_amdgcn_exp2f(x)
#else
#define EXP2(x) exp2f(x)
#endif

#define MFMA16(a,b,c) __builtin_amdgcn_mfma_f32_16x16x32_f16((a),(b),(c),0,0,0)
#define SCHED_FENCE() __builtin_amdgcn_sched_barrier(0)

__device__ inline f16x8 as_f16x8(uint4 u){
  union { uint4 u; f16x8 h; } v; v.u = u; return v.h;
}

// async global->LDS, 16B per lane; lds ptr must be wave-uniform (lane l lands at +l*16B)
__device__ inline void gl_lds16(const f16* g, f16* l){
  __builtin_amdgcn_global_load_lds(
      (const __attribute__((address_space(1))) void*)g,
      (__attribute__((address_space(3))) void*)l, 16, 0, 0);
}

// ---------------- fp32 -> f16 convert (all three tensors, one launch) ----------------
#define CVT_N1 (NM*NC/4)      // 3145728
#define CVT_N2 (QKVC*NC/4)    // 442368
#define CVT_N3 (NC*NC/4)      // 147456
__global__ void cvt_all(const float* __restrict__ x, const float* __restrict__ wq,
                        const float* __restrict__ wp, f16* __restrict__ xh,
                        f16* __restrict__ wqh, f16* __restrict__ wph){
  int i = blockIdx.x*blockDim.x + threadIdx.x;
  const float* in; f16* out; int j;
  if (i < CVT_N1){ in = x; out = xh; j = i; }
  else if (i < CVT_N1 + CVT_N2){ in = wq; out = wqh; j = i - CVT_N1; }
  else { in = wp; out = wph; j = i - CVT_N1 - CVT_N2; }
  float4 v = ((const float4*)in)[j];
  f16x4 h; h[0]=(f16)v.x; h[1]=(f16)v.y; h[2]=(f16)v.z; h[3]=(f16)v.w;
  ((f16x4*)out)[j] = h;
}

// ---------------- 256x256 / BK=64 GEMM body (shared by qkv/proj) ----------------
// 512 thr = 8 waves (2 wr x 4 wc), per-wave output 128x64. LDS: sA/sB
// [2][256 rows][8 slots of 16B], slot swizzled: phys = logical ^ (row&7).
// Stage: thread t covers slot g = j*512+t (linear DMA dest), source column
// pre-swizzled: sslot = (t&7)^((t>>3)&7). Per K-tile: vmcnt(0) [old loads],
// barrier, stage A(next), compute khalf0, stage B(next), compute khalf1.
#define G_STAGE(SRC, DSTB, KT, RC0)                                           \
  _Pragma("unroll")                                                           \
  for (int j = 0; j < 4; j++){                                                \
    const int r_ = j*64 + (t >> 3);                                           \
    gl_lds16(SRC + (size_t)((RC0) + r_)*NC + (KT) + sslot*8,                  \
             (DSTB) + j*4096 + wv*512);                                       \
  }

#define GEMM256_PIPELINE(SRC_A, SRC_B)                                        \
  G_STAGE(SRC_A, sA, 0, R0);                                                  \
  G_STAGE(SRC_B, sB, 0, C0);                                                  \
  _Pragma("unroll 1")                                                         \
  for (int tt = 0; tt < 12; tt++){                                            \
    const int cur = tt & 1;                                                   \
    asm volatile("s_waitcnt vmcnt(0)" ::: "memory");   /* tile-old loads */   \
    SCHED_FENCE();                                                            \
    __builtin_amdgcn_s_barrier();                      /* buf[cur] staged,  */\
    SCHED_FENCE();                                     /* buf[cur^1] free   */\
    const f16* A_ = sA + (cur ? 16384 : 0);                                   \
    const f16* B_ = sB + (cur ? 16384 : 0);                                   \
    f16* An_ = sA + (cur ? 0 : 16384);                                        \
    f16* Bn_ = sB + (cur ? 0 : 16384);                                        \
    if (tt < 11){ G_STAGE(SRC_A, An_, (tt+1)*64, R0); }                       \
    {                                                                         \
      f16x8 bf[4];                                                            \
      _Pragma("unroll")                                                       \
      for (int nt = 0; nt < 4; nt++)                                          \
        bf[nt] = as_f16x8(*(const uint4*)(B_ + (wc*64 + nt*16 + lr)*64 + kxA0)); \
      __builtin_amdgcn_s_setprio(1);                                          \
      _Pragma("unroll")                                                       \
      for (int mt = 0; mt < 8; mt++){                                         \
        f16x8 af = as_f16x8(*(const uint4*)(A_ + (wr*128 + mt*16 + lr)*64 + kxA0)); \
        _Pragma("unroll")                                                     \
        for (int nt = 0; nt < 4; nt++)                                        \
          acc[mt][nt] = MFMA16(af, bf[nt], acc[mt][nt]);                      \
      }                                                                       \
      __builtin_amdgcn_s_setprio(0);                                          \
    }                                                                         \
    if (tt < 11){ G_STAGE(SRC_B, Bn_, (tt+1)*64, C0); }                       \
    {                                                                         \
      f16x8 bf[4];                                                            \
      _Pragma("unroll")                                                       \
      for (int nt = 0; nt < 4; nt++)                                          \
        bf[nt] = as_f16x8(*(const uint4*)(B_ + (wc*64 + nt*16 + lr)*64 + kxA1)); \
      __builtin_amdgcn_s_setprio(1);                                          \
      _Pragma("unroll")                                                       \
      for (int mt = 0; mt < 8; mt++){                                         \
        f16x8 af = as_f16x8(*(const uint4*)(A_ + (wr*128 + mt*16 + lr)*64 + kxA1)); \
        _Pragma("unroll")                                                     \
        for (int nt = 0; nt < 4; nt++)                                        \
          acc[mt][nt] = MFMA16(af, bf[nt], acc[mt][nt]);                      \
      }                                                                       \
      __builtin_amdgcn_s_setprio(0);                                          \
    }                                                                         \
  }

#define GEMM256_PREAMBLE                                                      \
  const int R0 = blockIdx.y*256, C0 = blockIdx.x*256;                         \
  const int t = threadIdx.x;                                                  \
  const int wv = t >> 6, l = t & 63, quad = l >> 4, lr = l & 15;              \
  const int wr = wv >> 2, wc = wv & 3;                                        \
  const int sslot = (t & 7) ^ ((t >> 3) & 7);                                 \
  const int xr = lr & 7;                                                      \
  const int kxA0 = (quad ^ xr)*8;                                             \
  const int kxA1 = ((4 + quad) ^ xr)*8;                                       \
  f32x4 acc[8][4] = {};

// ---------------- QKV GEMM: [16384,768] x [2304,768]^T, 256x256 tile ----------------
__launch_bounds__(512, 2)
__global__ void gemm_qkv(const f16* __restrict__ X, const f16* __restrict__ W,
                         f16* __restrict__ Q, f16* __restrict__ K, f16* __restrict__ VT){
  __shared__ f16 sA[2*16384];   // 64 KB: 2 bufs x 256 rows x 64 k (swizzled slots)
  __shared__ f16 sB[2*16384];   // 64 KB
  GEMM256_PREAMBLE;
  GEMM256_PIPELINE(X, W);
  // scatter into Q / K / V^T. type uniform per block (256 | 768, 768=3*256).
  const int type = C0 / NC;
#pragma unroll
  for (int nt = 0; nt < 4; nt++){
    int colg = C0 + wc*64 + nt*16 + lr;
    int rem  = colg - type*NC;
    int hh = rem >> 6, d = rem & 63;
#pragma unroll
    for (int mt = 0; mt < 8; mt++)
#pragma unroll
      for (int i = 0; i < 4; i++){
        int row = R0 + wr*128 + mt*16 + quad*4 + i;
        int bb = row >> 10, np = row & 1023;
        int bh = bb*NH + hh;
        float a = acc[mt][nt][i];
        if (type == 0)      Q[(bh << 16) + (np << 6) + d] = (f16)(a * QSCALE);
        else if (type == 1) K[(bh << 16) + (np << 6) + d] = (f16)a;
        else                VT[(bh << 16) + (d << 10) + np] = (f16)a;
      }
  }
}

// ---------------- Vsum: column sums of V per (b,h) ----------------
__global__ void vsum_kernel(const f16* __restrict__ VT, float* __restrict__ vsum){
  int bh = blockIdx.x;
  int t = threadIdx.x;
  int row = t >> 2, part = t & 3;
  const uint4* p = (const uint4*)(VT + ((size_t)bh << 16) + row*NN + part*256);
  float s = 0.f;
#pragma unroll
  for (int i = 0; i < 32; i++){
    f16x8 v = as_f16x8(p[i]);
#pragma unroll
    for (int j = 0; j < 8; j++) s += (float)v[j];
  }
  __shared__ float sR[64][4];
  sR[row][part] = s;
  __syncthreads();
  if (t < 64) vsum[bh*64 + t] = sR[t][0] + sR[t][1] + sR[t][2] + sR[t][3];
}

// ---------------- fused policy-softmax attention (no-max-subtract) ----------------
// (unchanged from R9b — DMA pipeline, verified)
#define STAGE(BUF, KEY0H)                                                     \
  _Pragma("unroll")                                                           \
  for (int j = 0; j < 2; j++){                                                \
    const int s_  = j*256 + t;                                                \
    const int r_  = s_ >> 3;                                                  \
    const int sl_ = (s_ & 7) ^ (r_ & 7);                                      \
    f16* du_ = (f16*)&sK[BUF][(j*256 + (t & 192))*8];                         \
    f16* dv_ = (f16*)&sVT[BUF][(j*256 + (t & 192))*8];                        \
    gl_lds16(Kg  + (size_t)((KEY0H) + r_)*HD + sl_*8, du_);                   \
    gl_lds16(VTg + (size_t)r_*NN + (KEY0H) + sl_*8,   dv_);                   \
  }

__launch_bounds__(256, 3)
__global__ void attn_kernel(const f16* __restrict__ Q, const f16* __restrict__ K,
                            const f16* __restrict__ VT, const float* __restrict__ policy,
                            const float* __restrict__ vsum, f16* __restrict__ O){
  __shared__ f16 sK[2][4096];          // 16 KB: 64 keys x 64 d, swizzled
  __shared__ f16 sVT[2][4096];         // 16 KB: 64 d x 64 keys, swizzled
  __shared__ f16 sP[4][2][16][PSTR];   // 17408 B
  __shared__ float sPol[1024];         // 4096 B  -> total 53 KB, 3 blocks/CU

  const int blk = blockIdx.x;
  const int bh = blk % (NB*NH);
  const int qt = blk / (NB*NH);
  const int b = bh / NH;
  const size_t base = (size_t)bh << 16;

  const int t = threadIdx.x;
  const int w = t >> 6, l = t & 63, quad = l >> 4, lr = l & 15;
  const int q0 = qt*128 + w*32;
  const int qrow = q0 + lr;
  const int h = bh - b*NH;
  const int xr = lr & 7;                       // row&7 for all tile rows (16-aligned)
  const int kx0 = (quad ^ xr)*8;               // swizzled f16 offset, d 0..31 slot
  const int kx1 = ((4 + quad) ^ xr)*8;         // d 32..63 slot

  *(float4*)&sPol[t*4] = *(const float4*)(policy + b*NN + t*4);

  // Q fragments (pre-scaled), contiguous 16B global reads
  f16x8 qf[2][2];
#pragma unroll
  for (int tq = 0; tq < 2; tq++)
#pragma unroll
    for (int hf = 0; hf < 2; hf++)
      qf[tq][hf] = as_f16x8(*(const uint4*)(Q + base + (size_t)(q0 + tq*16 + lr)*HD + hf*32 + quad*8));

  float vs[4];
#pragma unroll
  for (int nt = 0; nt < 4; nt++) vs[nt] = vsum[bh*64 + nt*16 + lr];

  f16x8 ones;
#pragma unroll
  for (int j = 0; j < 8; j++) ones[j] = (f16)1.0f;

  float m_run[2] = {-INFINITY, -INFINITY};
  f32x4 acc_l[2] = {};
  f32x4 o[2][4] = {};

  const f16* Kg  = K + base;
  const f16* VTg = VT + base;

  // prologue: stage step 0, drain everything (incl. qf/vs vmem + sPol lds)
  STAGE(0, 0);
  asm volatile("s_waitcnt vmcnt(0) lgkmcnt(0)" ::: "memory");
  SCHED_FENCE();
  __builtin_amdgcn_s_barrier();
  SCHED_FENCE();

#pragma unroll 1
  for (int hs = 0; hs < 16; hs++){
    const int cur = hs & 1;
    const int key0h = hs*64;
    if (hs < 15){
      STAGE(cur^1, key0h + 64);
      asm volatile("s_waitcnt vmcnt(4)" ::: "memory");   // drain prev stage, keep 4 in flight
    } else {
      asm volatile("s_waitcnt vmcnt(0)" ::: "memory");
    }
    SCHED_FENCE();
    __builtin_amdgcn_s_barrier();                        // buf[cur] fully staged (all waves)
    SCHED_FENCE();

    const f16* sKc = (const f16*)sK[cur];
    const f16* sVc = (const f16*)sVT[cur];

    // ---- S^T = K · Q^T for 64 keys (rows) x 32 queries
    f32x4 accA[4], accB[4];
#pragma unroll
    for (int ct = 0; ct < 4; ct++){ accA[ct] = (f32x4){0,0,0,0}; accB[ct] = (f32x4){0,0,0,0}; }
    __builtin_amdgcn_s_setprio(1);
#pragma unroll
    for (int ct = 0; ct < 4; ct++){
      const f16* kp = sKc + (ct*16 + lr)*64;
      f16x8 k0 = as_f16x8(*(const uint4*)(kp + kx0));
      f16x8 k1 = as_f16x8(*(const uint4*)(kp + kx1));
      accA[ct] = MFMA16(k0, qf[0][0], accA[ct]);
      accA[ct] = MFMA16(k1, qf[0][1], accA[ct]);
      accB[ct] = MFMA16(k0, qf[1][0], accB[ct]);
      accB[ct] = MFMA16(k1, qf[1][1], accB[ct]);
    }
    __builtin_amdgcn_s_setprio(0);

    // ---- softmax * policy -> sP (per-wave tile), running max
    {
      float mA = m_run[0], mB = m_run[1];
      const bool diag = (hs == 2*qt + (w >> 1));         // wave-uniform
      if (!diag){
#pragma unroll
        for (int ct = 0; ct < 4; ct++){
          const int kb = ct*16 + quad*4;
          float4 pol4 = *(const float4*)&sPol[key0h + kb];
          const float* p4 = (const float*)&pol4;
          mA = fmaxf(mA, fmaxf(fmaxf(accA[ct][0], accA[ct][1]), fmaxf(accA[ct][2], accA[ct][3])));
          mB = fmaxf(mB, fmaxf(fmaxf(accB[ct][0], accB[ct][1]), fmaxf(accB[ct][2], accB[ct][3])));
          union { f16x4 v; fp16x2 h[2]; } uA, uB;
          uA.h[0] = __builtin_amdgcn_cvt_pkrtz(EXP2(accA[ct][0])*p4[0], EXP2(accA[ct][1])*p4[1]);
          uA.h[1] = __builtin_amdgcn_cvt_pkrtz(EXP2(accA[ct][2])*p4[2], EXP2(accA[ct][3])*p4[3]);
          uB.h[0] = __builtin_amdgcn_cvt_pkrtz(EXP2(accB[ct][0])*p4[0], EXP2(accB[ct][1])*p4[1]);
          uB.h[1] = __builtin_amdgcn_cvt_pkrtz(EXP2(accB[ct][2])*p4[2], EXP2(accB[ct][3])*p4[3]);
          *(f16x4*)&sP[w][0][lr][kb] = uA.v;
          *(f16x4*)&sP[w][1][lr][kb] = uB.v;
        }
      } else {
#pragma unroll
        for (int ct = 0; ct < 4; ct++){
          const int kb = ct*16 + quad*4;
          float4 pol4 = *(const float4*)&sPol[key0h + kb];
          const float* p4 = (const float*)&pol4;
          float eA[4], eB[4];
#pragma unroll
          for (int i2 = 0; i2 < 4; i2++){
            int kg = key0h + kb + i2;
            float polA = (kg == qrow)      ? 1.0f : p4[i2];
            float polB = (kg == qrow + 16) ? 1.0f : p4[i2];
            mA = fmaxf(mA, accA[ct][i2]); mB = fmaxf(mB, accB[ct][i2]);
            eA[i2] = EXP2(accA[ct][i2]) * polA;
            eB[i2] = EXP2(accB[ct][i2]) * polB;
          }
          union { f16x4 v; fp16x2 h[2]; } uA, uB;
          uA.h[0] = __builtin_amdgcn_cvt_pkrtz(eA[0], eA[1]);
          uA.h[1] = __builtin_amdgcn_cvt_pkrtz(eA[2], eA[3]);
          uB.h[0] = __builtin_amdgcn_cvt_pkrtz(eB[0], eB[1]);
          uB.h[1] = __builtin_amdgcn_cvt_pkrtz(eB[2], eB[3]);
          *(f16x4*)&sP[w][0][lr][kb] = uA.v;
          *(f16x4*)&sP[w][1][lr][kb] = uB.v;
        }
      }
      m_run[0] = mA; m_run[1] = mB;
    }

    // ---- O += P V^T ; l += P * ones (both MFMA, all operands from LDS)
    __builtin_amdgcn_s_setprio(1);
#pragma unroll
    for (int s8g = 0; s8g < 2; s8g++){
      f16x8 pfA = as_f16x8(*(const uint4*)&sP[w][0][lr][s8g*32 + quad*8]);
      f16x8 pfB = as_f16x8(*(const uint4*)&sP[w][1][lr][s8g*32 + quad*8]);
      acc_l[0] = MFMA16(pfA, ones, acc_l[0]);
      acc_l[1] = MFMA16(pfB, ones, acc_l[1]);
      const int sx = ((s8g*4 + quad) ^ xr)*8;            // swizzled key-slot offset
#pragma unroll
      for (int nt = 0; nt < 4; nt++){
        f16x8 vf = as_f16x8(*(const uint4*)(sVc + (nt*16 + lr)*64 + sx));
        o[0][nt] = MFMA16(pfA, vf, o[0][nt]);
        o[1][nt] = MFMA16(pfB, vf, o[1][nt]);
      }
    }
    __builtin_amdgcn_s_setprio(0);
    SCHED_FENCE();
    __builtin_amdgcn_s_barrier();                        // all waves done with buf[cur]
    SCHED_FENCE();
  }

  // ---- epilogue: out = (O + eps/N * E * Vsum) / (l + eps * E)
#pragma unroll
  for (int tq = 0; tq < 2; tq++){
    float mq = m_run[tq];
    mq = fmaxf(mq, __shfl_xor(mq, 16));
    mq = fmaxf(mq, __shfl_xor(mq, 32));   // per-query (lr) global max, all lanes
#pragma unroll
    for (int i = 0; i < 4; i++){
      float mi = __shfl(mq, quad*4 + i);  // max for query row quad*4+i
      float E  = EXP2(mi);
      float li = acc_l[tq][i];            // row-sum for this query
      float inv = 1.0f / (li + 1e-6f*E);
      float ec  = (1e-6f/1024.0f)*E;
      int row = q0 + tq*16 + quad*4 + i;
      f16* op = O + (size_t)(b*NN + row)*NC + h*HD;
#pragma unroll
      for (int nt = 0; nt < 4; nt++)
        op[nt*16 + lr] = (f16)((o[tq][nt][i] + ec*vs[nt]) * inv);
    }
  }
}

// ---------------- proj GEMM: [16384,768] x [768,768]^T + bias -> fp32, 256x256 ----------------
__launch_bounds__(512, 2)
__global__ void gemm_proj(const f16* __restrict__ A, const f16* __restrict__ W,
                          const float* __restrict__ bias, float* __restrict__ out){
  __shared__ f16 sA[2*16384];
  __shared__ f16 sB[2*16384];
  GEMM256_PREAMBLE;
  GEMM256_PIPELINE(A, W);
#pragma unroll
  for (int nt = 0; nt < 4; nt++){
    int colg = C0 + wc*64 + nt*16 + lr;
    float bv = bias[colg];
#pragma unroll
    for (int mt = 0; mt < 8; mt++)
#pragma unroll
      for (int i = 0; i < 4; i++){
        int row = R0 + wr*128 + mt*16 + quad*4 + i;
        out[(size_t)row*NC + colg] = acc[mt][nt][i] + bv;
      }
  }
}

extern "C" void kernel_launch(void* const* d_in, const int* in_sizes, int n_in,
                              void* d_out, int out_size, void* d_ws, size_t ws_size,
                              hipStream_t stream) {
  const float* x      = (const float*)d_in[0];
  const float* policy = (const float*)d_in[1];
  const float* w_qkv  = (const float*)d_in[2];
  const float* w_proj = (const float*)d_in[3];
  const float* b_proj = (const float*)d_in[4];
  float* out = (float*)d_out;

  f16* x_h     = (f16*)d_ws;
  f16* wqkv_h  = x_h + (size_t)NM*NC;
  f16* wproj_h = wqkv_h + (size_t)QKVC*NC;
  f16* q_h     = wproj_h + (size_t)NC*NC;
  f16* k_h     = q_h + (size_t)NM*NC;
  f16* vt_h    = k_h + (size_t)NM*NC;
  float* vsum_f = (float*)(vt_h + (size_t)NM*NC);
  f16* attn_h  = x_h;   // x dead after gemm_qkv -> reuse

  cvt_all<<<(CVT_N1+CVT_N2+CVT_N3)/256, 256, 0, stream>>>(x, w_qkv, w_proj, x_h, wqkv_h, wproj_h);

  gemm_qkv<<<dim3(QKVC/256, NM/256), 512, 0, stream>>>(x_h, wqkv_h, q_h, k_h, vt_h);

  vsum_kernel<<<dim3(NB*NH), 256, 0, stream>>>(vt_h, vsum_f);

  attn_kernel<<<dim3(NB*NH*(NN/128)), 256, 0, stream>>>(q_h, k_h, vt_h, policy, vsum_f, attn_h);

  gemm_proj<<<dim3(NC/256, NM/256), 512, 0, stream>>>(attn_h, wproj_h, b_proj, out);
}

// Round 8
// 343.245 us; speedup vs baseline: 1.0142x; 1.0142x over previous
//
#include <hip/hip_runtime.h>

// Attention with policy-softmax, MI355X (gfx950).
// Shapes: B=16, N=1024, C=768, H=12, hd=64.
// R13: GEMMs get the genuine m201 8-phase schedule. R12 (256^2, 1 barrier/
// K-tile) proved geometry alone is null: all 8 waves burst ds_reads (2.3k cy
// LDS-serialized, MFMA idle) then burst MFMA (LDS idle) -> MfmaUtil 17%.
// R13 splits each K-tile into 4 phases: {ds_read cluster | 2x gl_lds stage |
// barrier | lgkmcnt(0) | setprio+16 MFMA | barrier} -- the double barrier
// per phase role-splits waves so LDS reads and MFMA overlap across waves
// (T3's actual mechanism; T5 pays only in this structure). vmcnt(0) once per
// tile (own stages, ~4 phases old). Bijective XCD swizzle on both GEMM grids.
// attn unchanged from R9b (proven).

#define NB 16
#define NN 1024
#define NC 768
#define NH 12
#define HD 64
#define NM (NB*NN)      // 16384
#define QKVC (3*NC)     // 2304
#define QSCALE 0.18033688011112042f   // 0.125 * log2(e)
#define PSTR 68         // attn sP row stride in f16 (136B)

typedef _Float16 f16;
typedef _Float16 f16x8 __attribute__((ext_vector_type(8)));
typedef _Float16 f16x4 __attribute__((ext_vector_type(4)));
typedef __fp16 fp16x2 __attribute__((ext_vector_type(2)));   // cvt_pkrtz native type
typedef float f32x4 __attribute__((ext_vector_type(4)));

#if __has_builtin(__builtin_amdgcn_exp2f)
#define EXP2(x) __builtin_amdgcn_exp2f(x)
#else
#define EXP2(x) exp2f(x)
#endif

#define MFMA16(a,b,c) __builtin_amdgcn_mfma_f32_16x16x32_f16((a),(b),(c),0,0,0)
#define SCHED_FENCE() __builtin_amdgcn_sched_barrier(0)

__device__ inline f16x8 as_f16x8(uint4 u){
  union { uint4 u; f16x8 h; } v; v.u = u; return v.h;
}

// async global->LDS, 16B per lane; lds ptr must be wave-uniform (lane l lands at +l*16B)
__device__ inline void gl_lds16(const f16* g, f16* l){
  __builtin_amdgcn_global_load_lds(
      (const __attribute__((address_space(1))) void*)g,
      (__attribute__((address_space(3))) void*)l, 16, 0, 0);
}

// ---------------- fp32 -> f16 convert (all three tensors, one launch) ----------------
#define CVT_N1 (NM*NC/4)      // 3145728
#define CVT_N2 (QKVC*NC/4)    // 442368
#define CVT_N3 (NC*NC/4)      // 147456
__global__ void cvt_all(const float* __restrict__ x, const float* __restrict__ wq,
                        const float* __restrict__ wp, f16* __restrict__ xh,
                        f16* __restrict__ wqh, f16* __restrict__ wph){
  int i = blockIdx.x*blockDim.x + threadIdx.x;
  const float* in; f16* out; int j;
  if (i < CVT_N1){ in = x; out = xh; j = i; }
  else if (i < CVT_N1 + CVT_N2){ in = wq; out = wqh; j = i - CVT_N1; }
  else { in = wp; out = wph; j = i - CVT_N1 - CVT_N2; }
  float4 v = ((const float4*)in)[j];
  f16x4 h; h[0]=(f16)v.x; h[1]=(f16)v.y; h[2]=(f16)v.z; h[3]=(f16)v.w;
  ((f16x4*)out)[j] = h;
}

// ---------------- 256x256 / BK=64 GEMM, 8-phase schedule ----------------
// 512 thr = 8 waves (2 wr x 4 wc), per-wave output 128x64. LDS: sA/sB
// [2][256 rows][8 slots of 16B], slot swizzled: phys = logical ^ (row&7).
// Stage: linear DMA dest, pre-swizzled global source (rule #21).
// Per K-tile: vmcnt(0)+barrier (buf[cur] ready), then 4 phases:
//   {ds_read cluster; 2x gl_lds(next); barrier; lgkmcnt(0); 16 MFMA; barrier}
#define G_STAGE1(SRC, DSTB, KT, RC0, J)                                       \
  gl_lds16(SRC + (size_t)((RC0) + (J)*64 + (t >> 3))*NC + (KT) + sslot*8,     \
           (DSTB) + (J)*4096 + wv*512);

#define G_STAGE4(SRC, DSTB, KT, RC0)                                          \
  { G_STAGE1(SRC, DSTB, KT, RC0, 0) G_STAGE1(SRC, DSTB, KT, RC0, 1)           \
    G_STAGE1(SRC, DSTB, KT, RC0, 2) G_STAGE1(SRC, DSTB, KT, RC0, 3) }

#define PH_READ_BF(KX)                                                        \
  _Pragma("unroll")                                                           \
  for (int nt = 0; nt < 4; nt++)                                              \
    bf[nt] = as_f16x8(*(const uint4*)(B_ + (wc*64 + nt*16 + lr)*64 + (KX)));

#define PH_READ_AF(M0, KX)                                                    \
  _Pragma("unroll")                                                           \
  for (int mt = 0; mt < 4; mt++)                                              \
    af[mt] = as_f16x8(*(const uint4*)(A_ + (wr*128 + ((M0)+mt)*16 + lr)*64 + (KX)));

#define PH_MFMA(M0)                                                           \
  asm volatile("s_waitcnt lgkmcnt(0)" ::: "memory");                          \
  SCHED_FENCE();                                                              \
  __builtin_amdgcn_s_setprio(1);                                              \
  _Pragma("unroll")                                                           \
  for (int mt = 0; mt < 4; mt++)                                              \
    _Pragma("unroll")                                                         \
    for (int nt = 0; nt < 4; nt++)                                            \
      acc[(M0)+mt][nt] = MFMA16(af[mt], bf[nt], acc[(M0)+mt][nt]);            \
  __builtin_amdgcn_s_setprio(0);                                              \
  SCHED_FENCE();

#define GEMM256_PIPELINE(SRC_A, SRC_B)                                        \
  G_STAGE4(SRC_A, sA, 0, R0);                                                 \
  G_STAGE4(SRC_B, sB, 0, C0);                                                 \
  _Pragma("unroll 1")                                                         \
  for (int tt = 0; tt < 12; tt++){                                            \
    const int cur = tt & 1;                                                   \
    const int kn = (tt + 1)*64;                                               \
    const bool st = (tt < 11);                                                \
    asm volatile("s_waitcnt vmcnt(0)" ::: "memory");   /* own tile-old DMA */ \
    SCHED_FENCE();                                                            \
    __builtin_amdgcn_s_barrier();                      /* buf[cur] ready   */ \
    SCHED_FENCE();                                                            \
    const f16* A_ = sA + (cur ? 16384 : 0);                                   \
    const f16* B_ = sB + (cur ? 16384 : 0);                                   \
    f16* An_ = sA + (cur ? 0 : 16384);                                        \
    f16* Bn_ = sB + (cur ? 0 : 16384);                                        \
    f16x8 af[4], bf[4];                                                       \
    /* phase 0: khalf0, acc[0..3] */                                          \
    PH_READ_BF(kxA0); PH_READ_AF(0, kxA0);                                    \
    SCHED_FENCE();                                                            \
    if (st){ G_STAGE1(SRC_A, An_, kn, R0, 0) G_STAGE1(SRC_A, An_, kn, R0, 1) }\
    SCHED_FENCE();                                                            \
    __builtin_amdgcn_s_barrier();                                             \
    PH_MFMA(0);                                                               \
    __builtin_amdgcn_s_barrier();                                             \
    SCHED_FENCE();                                                            \
    /* phase 1: khalf0, acc[4..7] */                                          \
    PH_READ_AF(4, kxA0);                                                      \
    SCHED_FENCE();                                                            \
    if (st){ G_STAGE1(SRC_A, An_, kn, R0, 2) G_STAGE1(SRC_A, An_, kn, R0, 3) }\
    SCHED_FENCE();                                                            \
    __builtin_amdgcn_s_barrier();                                             \
    PH_MFMA(4);                                                               \
    __builtin_amdgcn_s_barrier();                                             \
    SCHED_FENCE();                                                            \
    /* phase 2: khalf1, acc[0..3] */                                          \
    PH_READ_BF(kxA1); PH_READ_AF(0, kxA1);                                    \
    SCHED_FENCE();                                                            \
    if (st){ G_STAGE1(SRC_B, Bn_, kn, C0, 0) G_STAGE1(SRC_B, Bn_, kn, C0, 1) }\
    SCHED_FENCE();                                                            \
    __builtin_amdgcn_s_barrier();                                             \
    PH_MFMA(0);                                                               \
    __builtin_amdgcn_s_barrier();                                             \
    SCHED_FENCE();                                                            \
    /* phase 3: khalf1, acc[4..7] */                                          \
    PH_READ_AF(4, kxA1);                                                      \
    SCHED_FENCE();                                                            \
    if (st){ G_STAGE1(SRC_B, Bn_, kn, C0, 2) G_STAGE1(SRC_B, Bn_, kn, C0, 3) }\
    SCHED_FENCE();                                                            \
    __builtin_amdgcn_s_barrier();                                             \
    PH_MFMA(4);                                                               \
    __builtin_amdgcn_s_barrier();                                             \
    SCHED_FENCE();                                                            \
  }

// NBX = blocks in x (columns). Bijective XCD remap (grid % 8 == 0), then
// x-fastest decompose: each XCD owns a contiguous row-band (L2 panel reuse).
#define GEMM256_PREAMBLE(NBX, NWG)                                            \
  const int flat_ = blockIdx.y*(NBX) + blockIdx.x;                            \
  const int wg_ = (flat_ % 8)*((NWG)/8) + flat_/8;                            \
  const int R0 = (wg_/(NBX))*256, C0 = (wg_%(NBX))*256;                       \
  const int t = threadIdx.x;                                                  \
  const int wv = t >> 6, l = t & 63, quad = l >> 4, lr = l & 15;              \
  const int wr = wv >> 2, wc = wv & 3;                                        \
  const int sslot = (t & 7) ^ ((t >> 3) & 7);                                 \
  const int xr = lr & 7;                                                      \
  const int kxA0 = (quad ^ xr)*8;                                             \
  const int kxA1 = ((4 + quad) ^ xr)*8;                                       \
  f32x4 acc[8][4] = {};

// ---------------- QKV GEMM: [16384,768] x [2304,768]^T, 256x256 tile ----------------
__launch_bounds__(512, 2)
__global__ void gemm_qkv(const f16* __restrict__ X, const f16* __restrict__ W,
                         f16* __restrict__ Q, f16* __restrict__ K, f16* __restrict__ VT){
  __shared__ f16 sA[2*16384];   // 64 KB: 2 bufs x 256 rows x 64 k (swizzled slots)
  __shared__ f16 sB[2*16384];   // 64 KB
  GEMM256_PREAMBLE(9, 576);
  GEMM256_PIPELINE(X, W);
  // scatter into Q / K / V^T. type uniform per block (256 | 768, 768=3*256).
  const int type = C0 / NC;
#pragma unroll
  for (int nt = 0; nt < 4; nt++){
    int colg = C0 + wc*64 + nt*16 + lr;
    int rem  = colg - type*NC;
    int hh = rem >> 6, d = rem & 63;
#pragma unroll
    for (int mt = 0; mt < 8; mt++)
#pragma unroll
      for (int i = 0; i < 4; i++){
        int row = R0 + wr*128 + mt*16 + quad*4 + i;
        int bb = row >> 10, np = row & 1023;
        int bh = bb*NH + hh;
        float a = acc[mt][nt][i];
        if (type == 0)      Q[(bh << 16) + (np << 6) + d] = (f16)(a * QSCALE);
        else if (type == 1) K[(bh << 16) + (np << 6) + d] = (f16)a;
        else                VT[(bh << 16) + (d << 10) + np] = (f16)a;
      }
  }
}

// ---------------- Vsum: column sums of V per (b,h) ----------------
__global__ void vsum_kernel(const f16* __restrict__ VT, float* __restrict__ vsum){
  int bh = blockIdx.x;
  int t = threadIdx.x;
  int row = t >> 2, part = t & 3;
  const uint4* p = (const uint4*)(VT + ((size_t)bh << 16) + row*NN + part*256);
  float s = 0.f;
#pragma unroll
  for (int i = 0; i < 32; i++){
    f16x8 v = as_f16x8(p[i]);
#pragma unroll
    for (int j = 0; j < 8; j++) s += (float)v[j];
  }
  __shared__ float sR[64][4];
  sR[row][part] = s;
  __syncthreads();
  if (t < 64) vsum[bh*64 + t] = sR[t][0] + sR[t][1] + sR[t][2] + sR[t][3];
}

// ---------------- fused policy-softmax attention (no-max-subtract) ----------------
// (unchanged from R9b — DMA pipeline, verified)
#define STAGE(BUF, KEY0H)                                                     \
  _Pragma("unroll")                                                           \
  for (int j = 0; j < 2; j++){                                                \
    const int s_  = j*256 + t;                                                \
    const int r_  = s_ >> 3;                                                  \
    const int sl_ = (s_ & 7) ^ (r_ & 7);                                      \
    f16* du_ = (f16*)&sK[BUF][(j*256 + (t & 192))*8];                         \
    f16* dv_ = (f16*)&sVT[BUF][(j*256 + (t & 192))*8];                        \
    gl_lds16(Kg  + (size_t)((KEY0H) + r_)*HD + sl_*8, du_);                   \
    gl_lds16(VTg + (size_t)r_*NN + (KEY0H) + sl_*8,   dv_);                   \
  }

__launch_bounds__(256, 3)
__global__ void attn_kernel(const f16* __restrict__ Q, const f16* __restrict__ K,
                            const f16* __restrict__ VT, const float* __restrict__ policy,
                            const float* __restrict__ vsum, f16* __restrict__ O){
  __shared__ f16 sK[2][4096];          // 16 KB: 64 keys x 64 d, swizzled
  __shared__ f16 sVT[2][4096];         // 16 KB: 64 d x 64 keys, swizzled
  __shared__ f16 sP[4][2][16][PSTR];   // 17408 B
  __shared__ float sPol[1024];         // 4096 B  -> total 53 KB, 3 blocks/CU

  const int blk = blockIdx.x;
  const int bh = blk % (NB*NH);
  const int qt = blk / (NB*NH);
  const int b = bh / NH;
  const size_t base = (size_t)bh << 16;

  const int t = threadIdx.x;
  const int w = t >> 6, l = t & 63, quad = l >> 4, lr = l & 15;
  const int q0 = qt*128 + w*32;
  const int qrow = q0 + lr;
  const int h = bh - b*NH;
  const int xr = lr & 7;                       // row&7 for all tile rows (16-aligned)
  const int kx0 = (quad ^ xr)*8;               // swizzled f16 offset, d 0..31 slot
  const int kx1 = ((4 + quad) ^ xr)*8;         // d 32..63 slot

  *(float4*)&sPol[t*4] = *(const float4*)(policy + b*NN + t*4);

  // Q fragments (pre-scaled), contiguous 16B global reads
  f16x8 qf[2][2];
#pragma unroll
  for (int tq = 0; tq < 2; tq++)
#pragma unroll
    for (int hf = 0; hf < 2; hf++)
      qf[tq][hf] = as_f16x8(*(const uint4*)(Q + base + (size_t)(q0 + tq*16 + lr)*HD + hf*32 + quad*8));

  float vs[4];
#pragma unroll
  for (int nt = 0; nt < 4; nt++) vs[nt] = vsum[bh*64 + nt*16 + lr];

  f16x8 ones;
#pragma unroll
  for (int j = 0; j < 8; j++) ones[j] = (f16)1.0f;

  float m_run[2] = {-INFINITY, -INFINITY};
  f32x4 acc_l[2] = {};
  f32x4 o[2][4] = {};

  const f16* Kg  = K + base;
  const f16* VTg = VT + base;

  // prologue: stage step 0, drain everything (incl. qf/vs vmem + sPol lds)
  STAGE(0, 0);
  asm volatile("s_waitcnt vmcnt(0) lgkmcnt(0)" ::: "memory");
  SCHED_FENCE();
  __builtin_amdgcn_s_barrier();
  SCHED_FENCE();

#pragma unroll 1
  for (int hs = 0; hs < 16; hs++){
    const int cur = hs & 1;
    const int key0h = hs*64;
    if (hs < 15){
      STAGE(cur^1, key0h + 64);
      asm volatile("s_waitcnt vmcnt(4)" ::: "memory");   // drain prev stage, keep 4 in flight
    } else {
      asm volatile("s_waitcnt vmcnt(0)" ::: "memory");
    }
    SCHED_FENCE();
    __builtin_amdgcn_s_barrier();                        // buf[cur] fully staged (all waves)
    SCHED_FENCE();

    const f16* sKc = (const f16*)sK[cur];
    const f16* sVc = (const f16*)sVT[cur];

    // ---- S^T = K · Q^T for 64 keys (rows) x 32 queries
    f32x4 accA[4], accB[4];
#pragma unroll
    for (int ct = 0; ct < 4; ct++){ accA[ct] = (f32x4){0,0,0,0}; accB[ct] = (f32x4){0,0,0,0}; }
    __builtin_amdgcn_s_setprio(1);
#pragma unroll
    for (int ct = 0; ct < 4; ct++){
      const f16* kp = sKc + (ct*16 + lr)*64;
      f16x8 k0 = as_f16x8(*(const uint4*)(kp + kx0));
      f16x8 k1 = as_f16x8(*(const uint4*)(kp + kx1));
      accA[ct] = MFMA16(k0, qf[0][0], accA[ct]);
      accA[ct] = MFMA16(k1, qf[0][1], accA[ct]);
      accB[ct] = MFMA16(k0, qf[1][0], accB[ct]);
      accB[ct] = MFMA16(k1, qf[1][1], accB[ct]);
    }
    __builtin_amdgcn_s_setprio(0);

    // ---- softmax * policy -> sP (per-wave tile), running max
    {
      float mA = m_run[0], mB = m_run[1];
      const bool diag = (hs == 2*qt + (w >> 1));         // wave-uniform
      if (!diag){
#pragma unroll
        for (int ct = 0; ct < 4; ct++){
          const int kb = ct*16 + quad*4;
          float4 pol4 = *(const float4*)&sPol[key0h + kb];
          const float* p4 = (const float*)&pol4;
          mA = fmaxf(mA, fmaxf(fmaxf(accA[ct][0], accA[ct][1]), fmaxf(accA[ct][2], accA[ct][3])));
          mB = fmaxf(mB, fmaxf(fmaxf(accB[ct][0], accB[ct][1]), fmaxf(accB[ct][2], accB[ct][3])));
          union { f16x4 v; fp16x2 h[2]; } uA, uB;
          uA.h[0] = __builtin_amdgcn_cvt_pkrtz(EXP2(accA[ct][0])*p4[0], EXP2(accA[ct][1])*p4[1]);
          uA.h[1] = __builtin_amdgcn_cvt_pkrtz(EXP2(accA[ct][2])*p4[2], EXP2(accA[ct][3])*p4[3]);
          uB.h[0] = __builtin_amdgcn_cvt_pkrtz(EXP2(accB[ct][0])*p4[0], EXP2(accB[ct][1])*p4[1]);
          uB.h[1] = __builtin_amdgcn_cvt_pkrtz(EXP2(accB[ct][2])*p4[2], EXP2(accB[ct][3])*p4[3]);
          *(f16x4*)&sP[w][0][lr][kb] = uA.v;
          *(f16x4*)&sP[w][1][lr][kb] = uB.v;
        }
      } else {
#pragma unroll
        for (int ct = 0; ct < 4; ct++){
          const int kb = ct*16 + quad*4;
          float4 pol4 = *(const float4*)&sPol[key0h + kb];
          const float* p4 = (const float*)&pol4;
          float eA[4], eB[4];
#pragma unroll
          for (int i2 = 0; i2 < 4; i2++){
            int kg = key0h + kb + i2;
            float polA = (kg == qrow)      ? 1.0f : p4[i2];
            float polB = (kg == qrow + 16) ? 1.0f : p4[i2];
            mA = fmaxf(mA, accA[ct][i2]); mB = fmaxf(mB, accB[ct][i2]);
            eA[i2] = EXP2(accA[ct][i2]) * polA;
            eB[i2] = EXP2(accB[ct][i2]) * polB;
          }
          union { f16x4 v; fp16x2 h[2]; } uA, uB;
          uA.h[0] = __builtin_amdgcn_cvt_pkrtz(eA[0], eA[1]);
          uA.h[1] = __builtin_amdgcn_cvt_pkrtz(eA[2], eA[3]);
          uB.h[0] = __builtin_amdgcn_cvt_pkrtz(eB[0], eB[1]);
          uB.h[1] = __builtin_amdgcn_cvt_pkrtz(eB[2], eB[3]);
          *(f16x4*)&sP[w][0][lr][kb] = uA.v;
          *(f16x4*)&sP[w][1][lr][kb] = uB.v;
        }
      }
      m_run[0] = mA; m_run[1] = mB;
    }

    // ---- O += P V^T ; l += P * ones (both MFMA, all operands from LDS)
    __builtin_amdgcn_s_setprio(1);
#pragma unroll
    for (int s8g = 0; s8g < 2; s8g++){
      f16x8 pfA = as_f16x8(*(const uint4*)&sP[w][0][lr][s8g*32 + quad*8]);
      f16x8 pfB = as_f16x8(*(const uint4*)&sP[w][1][lr][s8g*32 + quad*8]);
      acc_l[0] = MFMA16(pfA, ones, acc_l[0]);
      acc_l[1] = MFMA16(pfB, ones, acc_l[1]);
      const int sx = ((s8g*4 + quad) ^ xr)*8;            // swizzled key-slot offset
#pragma unroll
      for (int nt = 0; nt < 4; nt++){
        f16x8 vf = as_f16x8(*(const uint4*)(sVc + (nt*16 + lr)*64 + sx));
        o[0][nt] = MFMA16(pfA, vf, o[0][nt]);
        o[1][nt] = MFMA16(pfB, vf, o[1][nt]);
      }
    }
    __builtin_amdgcn_s_setprio(0);
    SCHED_FENCE();
    __builtin_amdgcn_s_barrier();                        // all waves done with buf[cur]
    SCHED_FENCE();
  }

  // ---- epilogue: out = (O + eps/N * E * Vsum) / (l + eps * E)
#pragma unroll
  for (int tq = 0; tq < 2; tq++){
    float mq = m_run[tq];
    mq = fmaxf(mq, __shfl_xor(mq, 16));
    mq = fmaxf(mq, __shfl_xor(mq, 32));   // per-query (lr) global max, all lanes
#pragma unroll
    for (int i = 0; i < 4; i++){
      float mi = __shfl(mq, quad*4 + i);  // max for query row quad*4+i
      float E  = EXP2(mi);
      float li = acc_l[tq][i];            // row-sum for this query
      float inv = 1.0f / (li + 1e-6f*E);
      float ec  = (1e-6f/1024.0f)*E;
      int row = q0 + tq*16 + quad*4 + i;
      f16* op = O + (size_t)(b*NN + row)*NC + h*HD;
#pragma unroll
      for (int nt = 0; nt < 4; nt++)
        op[nt*16 + lr] = (f16)((o[tq][nt][i] + ec*vs[nt]) * inv);
    }
  }
}

// ---------------- proj GEMM: [16384,768] x [768,768]^T + bias -> fp32, 256x256 ----------------
__launch_bounds__(512, 2)
__global__ void gemm_proj(const f16* __restrict__ A, const f16* __restrict__ W,
                          const float* __restrict__ bias, float* __restrict__ out){
  __shared__ f16 sA[2*16384];
  __shared__ f16 sB[2*16384];
  GEMM256_PREAMBLE(3, 192);
  GEMM256_PIPELINE(A, W);
#pragma unroll
  for (int nt = 0; nt < 4; nt++){
    int colg = C0 + wc*64 + nt*16 + lr;
    float bv = bias[colg];
#pragma unroll
    for (int mt = 0; mt < 8; mt++)
#pragma unroll
      for (int i = 0; i < 4; i++){
        int row = R0 + wr*128 + mt*16 + quad*4 + i;
        out[(size_t)row*NC + colg] = acc[mt][nt][i] + bv;
      }
  }
}

extern "C" void kernel_launch(void* const* d_in, const int* in_sizes, int n_in,
                              void* d_out, int out_size, void* d_ws, size_t ws_size,
                              hipStream_t stream) {
  const float* x      = (const float*)d_in[0];
  const float* policy = (const float*)d_in[1];
  const float* w_qkv  = (const float*)d_in[2];
  const float* w_proj = (const float*)d_in[3];
  const float* b_proj = (const float*)d_in[4];
  float* out = (float*)d_out;

  f16* x_h     = (f16*)d_ws;
  f16* wqkv_h  = x_h + (size_t)NM*NC;
  f16* wproj_h = wqkv_h + (size_t)QKVC*NC;
  f16* q_h     = wproj_h + (size_t)NC*NC;
  f16* k_h     = q_h + (size_t)NM*NC;
  f16* vt_h    = k_h + (size_t)NM*NC;
  float* vsum_f = (float*)(vt_h + (size_t)NM*NC);
  f16* attn_h  = x_h;   // x dead after gemm_qkv -> reuse

  cvt_all<<<(CVT_N1+CVT_N2+CVT_N3)/256, 256, 0, stream>>>(x, w_qkv, w_proj, x_h, wqkv_h, wproj_h);

  gemm_qkv<<<dim3(QKVC/256, NM/256), 512, 0, stream>>>(x_h, wqkv_h, q_h, k_h, vt_h);

  vsum_kernel<<<dim3(NB*NH), 256, 0, stream>>>(vt_h, vsum_f);

  attn_kernel<<<dim3(NB*NH*(NN/128)), 256, 0, stream>>>(q_h, k_h, vt_h, policy, vsum_f, attn_h);

  gemm_proj<<<dim3(NC/256, NM/256), 512, 0, stream>>>(attn_h, wproj_h, b_proj, out);
}

// Round 10
// 320.620 us; speedup vs baseline: 1.0858x; 1.0706x over previous
//
#include <hip/hip_runtime.h>

// Attention with policy-softmax, MI355X (gfx950).
// Shapes: B=16, N=1024, C=768, H=12, hd=64.
// R15: R14 transpose-epilogue bugfix. R14 failed (absmax 0.53): the coalesced
// VT store derived (hh,d) from the LOCAL column c, dropping the C0-2*NC block
// offset -> all three type-2 blocks wrote heads 0..3. Also TSTR=258 made the
// b128 LDS reads 4B-aligned (UB). R15: cg = (C0-2*NC)+c for head/d decompose;
// TSTR=264 (528B rows, 16B-aligned). Everything else identical to R14
// (R13 pipeline + XCD remap; attn from R9b).

#define NB 16
#define NN 1024
#define NC 768
#define NH 12
#define HD 64
#define NM (NB*NN)      // 16384
#define QKVC (3*NC)     // 2304
#define QSCALE 0.18033688011112042f   // 0.125 * log2(e)
#define PSTR 68         // attn sP row stride in f16 (136B)
#define TSTR 264        // transpose-LDS row stride in f16 (528B, 16B-aligned)

typedef _Float16 f16;
typedef _Float16 f16x8 __attribute__((ext_vector_type(8)));
typedef _Float16 f16x4 __attribute__((ext_vector_type(4)));
typedef _Float16 f16x2 __attribute__((ext_vector_type(2)));
typedef __fp16 fp16x2 __attribute__((ext_vector_type(2)));   // cvt_pkrtz native type
typedef float f32x4 __attribute__((ext_vector_type(4)));

#if __has_builtin(__builtin_amdgcn_exp2f)
#define EXP2(x) __builtin_amdgcn_exp2f(x)
#else
#define EXP2(x) exp2f(x)
#endif

#define MFMA16(a,b,c) __builtin_amdgcn_mfma_f32_16x16x32_f16((a),(b),(c),0,0,0)
#define SCHED_FENCE() __builtin_amdgcn_sched_barrier(0)

__device__ inline f16x8 as_f16x8(uint4 u){
  union { uint4 u; f16x8 h; } v; v.u = u; return v.h;
}

// async global->LDS, 16B per lane; lds ptr must be wave-uniform (lane l lands at +l*16B)
__device__ inline void gl_lds16(const f16* g, f16* l){
  __builtin_amdgcn_global_load_lds(
      (const __attribute__((address_space(1))) void*)g,
      (__attribute__((address_space(3))) void*)l, 16, 0, 0);
}

// ---------------- fp32 -> f16 convert (all three tensors, one launch) ----------------
#define CVT_N1 (NM*NC/4)      // 3145728
#define CVT_N2 (QKVC*NC/4)    // 442368
#define CVT_N3 (NC*NC/4)      // 147456
__global__ void cvt_all(const float* __restrict__ x, const float* __restrict__ wq,
                        const float* __restrict__ wp, f16* __restrict__ xh,
                        f16* __restrict__ wqh, f16* __restrict__ wph){
  int i = blockIdx.x*blockDim.x + threadIdx.x;
  const float* in; f16* out; int j;
  if (i < CVT_N1){ in = x; out = xh; j = i; }
  else if (i < CVT_N1 + CVT_N2){ in = wq; out = wqh; j = i - CVT_N1; }
  else { in = wp; out = wph; j = i - CVT_N1 - CVT_N2; }
  float4 v = ((const float4*)in)[j];
  f16x4 h; h[0]=(f16)v.x; h[1]=(f16)v.y; h[2]=(f16)v.z; h[3]=(f16)v.w;
  ((f16x4*)out)[j] = h;
}

// ---------------- 256x256 / BK=64 GEMM, 4-phase/K-tile schedule (R13) ----------------
#define G_STAGE1(SRC, DSTB, KT, RC0, J)                                       \
  gl_lds16(SRC + (size_t)((RC0) + (J)*64 + (t >> 3))*NC + (KT) + sslot*8,     \
           (DSTB) + (J)*4096 + wv*512);

#define G_STAGE4(SRC, DSTB, KT, RC0)                                          \
  { G_STAGE1(SRC, DSTB, KT, RC0, 0) G_STAGE1(SRC, DSTB, KT, RC0, 1)           \
    G_STAGE1(SRC, DSTB, KT, RC0, 2) G_STAGE1(SRC, DSTB, KT, RC0, 3) }

#define PH_READ_BF(KX)                                                        \
  _Pragma("unroll")                                                           \
  for (int nt = 0; nt < 4; nt++)                                              \
    bf[nt] = as_f16x8(*(const uint4*)(B_ + (wc*64 + nt*16 + lr)*64 + (KX)));

#define PH_READ_AF(M0, KX)                                                    \
  _Pragma("unroll")                                                           \
  for (int mt = 0; mt < 4; mt++)                                              \
    af[mt] = as_f16x8(*(const uint4*)(A_ + (wr*128 + ((M0)+mt)*16 + lr)*64 + (KX)));

#define PH_MFMA(M0)                                                           \
  asm volatile("s_waitcnt lgkmcnt(0)" ::: "memory");                          \
  SCHED_FENCE();                                                              \
  __builtin_amdgcn_s_setprio(1);                                              \
  _Pragma("unroll")                                                           \
  for (int mt = 0; mt < 4; mt++)                                              \
    _Pragma("unroll")                                                         \
    for (int nt = 0; nt < 4; nt++)                                            \
      acc[(M0)+mt][nt] = MFMA16(af[mt], bf[nt], acc[(M0)+mt][nt]);            \
  __builtin_amdgcn_s_setprio(0);                                              \
  SCHED_FENCE();

#define GEMM256_PIPELINE(SRC_A, SRC_B, SA, SB)                                \
  G_STAGE4(SRC_A, (SA), 0, R0);                                               \
  G_STAGE4(SRC_B, (SB), 0, C0);                                               \
  _Pragma("unroll 1")                                                         \
  for (int tt = 0; tt < 12; tt++){                                            \
    const int cur = tt & 1;                                                   \
    const int kn = (tt + 1)*64;                                               \
    const bool st = (tt < 11);                                                \
    asm volatile("s_waitcnt vmcnt(0)" ::: "memory");   /* own tile-old DMA */ \
    SCHED_FENCE();                                                            \
    __builtin_amdgcn_s_barrier();                      /* buf[cur] ready   */ \
    SCHED_FENCE();                                                            \
    const f16* A_ = (SA) + (cur ? 16384 : 0);                                 \
    const f16* B_ = (SB) + (cur ? 16384 : 0);                                 \
    f16* An_ = (SA) + (cur ? 0 : 16384);                                      \
    f16* Bn_ = (SB) + (cur ? 0 : 16384);                                      \
    f16x8 af[4], bf[4];                                                       \
    /* phase 0: khalf0, acc[0..3] */                                          \
    PH_READ_BF(kxA0); PH_READ_AF(0, kxA0);                                    \
    SCHED_FENCE();                                                            \
    if (st){ G_STAGE1(SRC_A, An_, kn, R0, 0) G_STAGE1(SRC_A, An_, kn, R0, 1) }\
    SCHED_FENCE();                                                            \
    __builtin_amdgcn_s_barrier();                                             \
    PH_MFMA(0);                                                               \
    __builtin_amdgcn_s_barrier();                                             \
    SCHED_FENCE();                                                            \
    /* phase 1: khalf0, acc[4..7] */                                          \
    PH_READ_AF(4, kxA0);                                                      \
    SCHED_FENCE();                                                            \
    if (st){ G_STAGE1(SRC_A, An_, kn, R0, 2) G_STAGE1(SRC_A, An_, kn, R0, 3) }\
    SCHED_FENCE();                                                            \
    __builtin_amdgcn_s_barrier();                                             \
    PH_MFMA(4);                                                               \
    __builtin_amdgcn_s_barrier();                                             \
    SCHED_FENCE();                                                            \
    /* phase 2: khalf1, acc[0..3] */                                          \
    PH_READ_BF(kxA1); PH_READ_AF(0, kxA1);                                    \
    SCHED_FENCE();                                                            \
    if (st){ G_STAGE1(SRC_B, Bn_, kn, C0, 0) G_STAGE1(SRC_B, Bn_, kn, C0, 1) }\
    SCHED_FENCE();                                                            \
    __builtin_amdgcn_s_barrier();                                             \
    PH_MFMA(0);                                                               \
    __builtin_amdgcn_s_barrier();                                             \
    SCHED_FENCE();                                                            \
    /* phase 3: khalf1, acc[4..7] */                                          \
    PH_READ_AF(4, kxA1);                                                      \
    SCHED_FENCE();                                                            \
    if (st){ G_STAGE1(SRC_B, Bn_, kn, C0, 2) G_STAGE1(SRC_B, Bn_, kn, C0, 3) }\
    SCHED_FENCE();                                                            \
    __builtin_amdgcn_s_barrier();                                             \
    PH_MFMA(4);                                                               \
    __builtin_amdgcn_s_barrier();                                             \
    SCHED_FENCE();                                                            \
  }

// NBX = blocks in x (columns). Bijective XCD remap (grid % 8 == 0), then
// x-fastest decompose: each XCD owns a contiguous row-band (L2 panel reuse).
#define GEMM256_PREAMBLE(NBX, NWG)                                            \
  const int flat_ = blockIdx.y*(NBX) + blockIdx.x;                            \
  const int wg_ = (flat_ % 8)*((NWG)/8) + flat_/8;                            \
  const int R0 = (wg_/(NBX))*256, C0 = (wg_%(NBX))*256;                       \
  const int t = threadIdx.x;                                                  \
  const int wv = t >> 6, l = t & 63, quad = l >> 4, lr = l & 15;              \
  const int wr = wv >> 2, wc = wv & 3;                                        \
  const int sslot = (t & 7) ^ ((t >> 3) & 7);                                 \
  const int xr = lr & 7;                                                      \
  const int kxA0 = (quad ^ xr)*8;                                             \
  const int kxA1 = ((4 + quad) ^ xr)*8;                                       \
  f32x4 acc[8][4] = {};

// ---------------- QKV GEMM: [16384,768] x [2304,768]^T, 256x256 tile ----------------
// smem: pipeline phase uses [0,131072B) as sA|sB; type-2 epilogue reuses the
// region as the 256x256 transpose buffer (stride TSTR=264 -> 135168B).
__launch_bounds__(512, 2)
__global__ void gemm_qkv(const f16* __restrict__ X, const f16* __restrict__ W,
                         f16* __restrict__ Q, f16* __restrict__ K, f16* __restrict__ VT){
  __shared__ __align__(16) f16 smem[256*TSTR];   // 135168 B
  f16* const sAp = smem;                          // 2 x 16384 f16
  f16* const sBp = smem + 32768;                  // 2 x 16384 f16
  GEMM256_PREAMBLE(9, 576);
  GEMM256_PIPELINE(X, W, sAp, sBp);
  // scatter into Q / K / V^T. type uniform per block (256 | 768, 768=3*256).
  const int type = C0 / NC;
  if (type != 2){
#pragma unroll
    for (int nt = 0; nt < 4; nt++){
      int colg = C0 + wc*64 + nt*16 + lr;
      int rem  = colg - type*NC;
      int hh = rem >> 6, d = rem & 63;
#pragma unroll
      for (int mt = 0; mt < 8; mt++)
#pragma unroll
        for (int i = 0; i < 4; i++){
          int row = R0 + wr*128 + mt*16 + quad*4 + i;
          int bb = row >> 10, np = row & 1023;
          int bh = bb*NH + hh;
          float a = acc[mt][nt][i];
          if (type == 0) Q[(bh << 16) + (np << 6) + d] = (f16)(a * QSCALE);
          else           K[(bh << 16) + (np << 6) + d] = (f16)a;
        }
    }
  } else {
    // ---- V: transpose 256x256 tile through LDS, store coalesced to VT ----
    // (pipeline's final s_barrier already fenced all sA/sB reads)
    f16* const sT = smem;      // [col 0..255][TSTR], elem = (f16)acc value
#pragma unroll
    for (int nt = 0; nt < 4; nt++){
      const int col = wc*64 + nt*16 + lr;          // local d-col 0..255
#pragma unroll
      for (int mt = 0; mt < 8; mt++){
        const int npl = wr*128 + mt*16 + quad*4;   // local row 0..255 (4 consec)
        f16x2 h0; h0[0] = (f16)acc[mt][nt][0]; h0[1] = (f16)acc[mt][nt][1];
        f16x2 h1; h1[0] = (f16)acc[mt][nt][2]; h1[1] = (f16)acc[mt][nt][3];
        *(f16x2*)&sT[col*TSTR + npl]     = h0;
        *(f16x2*)&sT[col*TSTR + npl + 2] = h1;
      }
    }
    __syncthreads();
    const int c    = t >> 1;                        // local d-col 0..255
    const int half = t & 1;                         // np half 0/1
    const int cg   = (C0 - 2*NC) + c;               // global V column 0..767
    const int bb   = R0 >> 10;                      // same b for whole block
    const int np0  = (R0 & 1023) + half*128;
    const int hh   = cg >> 6, d = cg & 63;
    const int bh   = bb*NH + hh;
    f16* dst = VT + ((size_t)bh << 16) + (d << 10) + np0;
    const f16* srcl = sT + c*TSTR + half*128;
#pragma unroll
    for (int j = 0; j < 16; j++)
      *(uint4*)(dst + j*8) = *(const uint4*)(srcl + j*8);
  }
}

// ---------------- Vsum: column sums of V per (b,h) ----------------
__global__ void vsum_kernel(const f16* __restrict__ VT, float* __restrict__ vsum){
  int bh = blockIdx.x;
  int t = threadIdx.x;
  int row = t >> 2, part = t & 3;
  const uint4* p = (const uint4*)(VT + ((size_t)bh << 16) + row*NN + part*256);
  float s = 0.f;
#pragma unroll
  for (int i = 0; i < 32; i++){
    f16x8 v = as_f16x8(p[i]);
#pragma unroll
    for (int j = 0; j < 8; j++) s += (float)v[j];
  }
  __shared__ float sR[64][4];
  sR[row][part] = s;
  __syncthreads();
  if (t < 64) vsum[bh*64 + t] = sR[t][0] + sR[t][1] + sR[t][2] + sR[t][3];
}

// ---------------- fused policy-softmax attention (no-max-subtract) ----------------
// (unchanged from R9b — DMA pipeline, verified)
#define STAGE(BUF, KEY0H)                                                     \
  _Pragma("unroll")                                                           \
  for (int j = 0; j < 2; j++){                                                \
    const int s_  = j*256 + t;                                                \
    const int r_  = s_ >> 3;                                                  \
    const int sl_ = (s_ & 7) ^ (r_ & 7);                                      \
    f16* du_ = (f16*)&sK[BUF][(j*256 + (t & 192))*8];                         \
    f16* dv_ = (f16*)&sVT[BUF][(j*256 + (t & 192))*8];                        \
    gl_lds16(Kg  + (size_t)((KEY0H) + r_)*HD + sl_*8, du_);                   \
    gl_lds16(VTg + (size_t)r_*NN + (KEY0H) + sl_*8,   dv_);                   \
  }

__launch_bounds__(256, 3)
__global__ void attn_kernel(const f16* __restrict__ Q, const f16* __restrict__ K,
                            const f16* __restrict__ VT, const float* __restrict__ policy,
                            const float* __restrict__ vsum, f16* __restrict__ O){
  __shared__ f16 sK[2][4096];          // 16 KB: 64 keys x 64 d, swizzled
  __shared__ f16 sVT[2][4096];         // 16 KB: 64 d x 64 keys, swizzled
  __shared__ f16 sP[4][2][16][PSTR];   // 17408 B
  __shared__ float sPol[1024];         // 4096 B  -> total 53 KB, 3 blocks/CU

  const int blk = blockIdx.x;
  const int bh = blk % (NB*NH);
  const int qt = blk / (NB*NH);
  const int b = bh / NH;
  const size_t base = (size_t)bh << 16;

  const int t = threadIdx.x;
  const int w = t >> 6, l = t & 63, quad = l >> 4, lr = l & 15;
  const int q0 = qt*128 + w*32;
  const int qrow = q0 + lr;
  const int h = bh - b*NH;
  const int xr = lr & 7;                       // row&7 for all tile rows (16-aligned)
  const int kx0 = (quad ^ xr)*8;               // swizzled f16 offset, d 0..31 slot
  const int kx1 = ((4 + quad) ^ xr)*8;         // d 32..63 slot

  *(float4*)&sPol[t*4] = *(const float4*)(policy + b*NN + t*4);

  // Q fragments (pre-scaled), contiguous 16B global reads
  f16x8 qf[2][2];
#pragma unroll
  for (int tq = 0; tq < 2; tq++)
#pragma unroll
    for (int hf = 0; hf < 2; hf++)
      qf[tq][hf] = as_f16x8(*(const uint4*)(Q + base + (size_t)(q0 + tq*16 + lr)*HD + hf*32 + quad*8));

  float vs[4];
#pragma unroll
  for (int nt = 0; nt < 4; nt++) vs[nt] = vsum[bh*64 + nt*16 + lr];

  f16x8 ones;
#pragma unroll
  for (int j = 0; j < 8; j++) ones[j] = (f16)1.0f;

  float m_run[2] = {-INFINITY, -INFINITY};
  f32x4 acc_l[2] = {};
  f32x4 o[2][4] = {};

  const f16* Kg  = K + base;
  const f16* VTg = VT + base;

  // prologue: stage step 0, drain everything (incl. qf/vs vmem + sPol lds)
  STAGE(0, 0);
  asm volatile("s_waitcnt vmcnt(0) lgkmcnt(0)" ::: "memory");
  SCHED_FENCE();
  __builtin_amdgcn_s_barrier();
  SCHED_FENCE();

#pragma unroll 1
  for (int hs = 0; hs < 16; hs++){
    const int cur = hs & 1;
    const int key0h = hs*64;
    if (hs < 15){
      STAGE(cur^1, key0h + 64);
      asm volatile("s_waitcnt vmcnt(4)" ::: "memory");   // drain prev stage, keep 4 in flight
    } else {
      asm volatile("s_waitcnt vmcnt(0)" ::: "memory");
    }
    SCHED_FENCE();
    __builtin_amdgcn_s_barrier();                        // buf[cur] fully staged (all waves)
    SCHED_FENCE();

    const f16* sKc = (const f16*)sK[cur];
    const f16* sVc = (const f16*)sVT[cur];

    // ---- S^T = K · Q^T for 64 keys (rows) x 32 queries
    f32x4 accA[4], accB[4];
#pragma unroll
    for (int ct = 0; ct < 4; ct++){ accA[ct] = (f32x4){0,0,0,0}; accB[ct] = (f32x4){0,0,0,0}; }
    __builtin_amdgcn_s_setprio(1);
#pragma unroll
    for (int ct = 0; ct < 4; ct++){
      const f16* kp = sKc + (ct*16 + lr)*64;
      f16x8 k0 = as_f16x8(*(const uint4*)(kp + kx0));
      f16x8 k1 = as_f16x8(*(const uint4*)(kp + kx1));
      accA[ct] = MFMA16(k0, qf[0][0], accA[ct]);
      accA[ct] = MFMA16(k1, qf[0][1], accA[ct]);
      accB[ct] = MFMA16(k0, qf[1][0], accB[ct]);
      accB[ct] = MFMA16(k1, qf[1][1], accB[ct]);
    }
    __builtin_amdgcn_s_setprio(0);

    // ---- softmax * policy -> sP (per-wave tile), running max
    {
      float mA = m_run[0], mB = m_run[1];
      const bool diag = (hs == 2*qt + (w >> 1));         // wave-uniform
      if (!diag){
#pragma unroll
        for (int ct = 0; ct < 4; ct++){
          const int kb = ct*16 + quad*4;
          float4 pol4 = *(const float4*)&sPol[key0h + kb];
          const float* p4 = (const float*)&pol4;
          mA = fmaxf(mA, fmaxf(fmaxf(accA[ct][0], accA[ct][1]), fmaxf(accA[ct][2], accA[ct][3])));
          mB = fmaxf(mB, fmaxf(fmaxf(accB[ct][0], accB[ct][1]), fmaxf(accB[ct][2], accB[ct][3])));
          union { f16x4 v; fp16x2 h[2]; } uA, uB;
          uA.h[0] = __builtin_amdgcn_cvt_pkrtz(EXP2(accA[ct][0])*p4[0], EXP2(accA[ct][1])*p4[1]);
          uA.h[1] = __builtin_amdgcn_cvt_pkrtz(EXP2(accA[ct][2])*p4[2], EXP2(accA[ct][3])*p4[3]);
          uB.h[0] = __builtin_amdgcn_cvt_pkrtz(EXP2(accB[ct][0])*p4[0], EXP2(accB[ct][1])*p4[1]);
          uB.h[1] = __builtin_amdgcn_cvt_pkrtz(EXP2(accB[ct][2])*p4[2], EXP2(accB[ct][3])*p4[3]);
          *(f16x4*)&sP[w][0][lr][kb] = uA.v;
          *(f16x4*)&sP[w][1][lr][kb] = uB.v;
        }
      } else {
#pragma unroll
        for (int ct = 0; ct < 4; ct++){
          const int kb = ct*16 + quad*4;
          float4 pol4 = *(const float4*)&sPol[key0h + kb];
          const float* p4 = (const float*)&pol4;
          float eA[4], eB[4];
#pragma unroll
          for (int i2 = 0; i2 < 4; i2++){
            int kg = key0h + kb + i2;
            float polA = (kg == qrow)      ? 1.0f : p4[i2];
            float polB = (kg == qrow + 16) ? 1.0f : p4[i2];
            mA = fmaxf(mA, accA[ct][i2]); mB = fmaxf(mB, accB[ct][i2]);
            eA[i2] = EXP2(accA[ct][i2]) * polA;
            eB[i2] = EXP2(accB[ct][i2]) * polB;
          }
          union { f16x4 v; fp16x2 h[2]; } uA, uB;
          uA.h[0] = __builtin_amdgcn_cvt_pkrtz(eA[0], eA[1]);
          uA.h[1] = __builtin_amdgcn_cvt_pkrtz(eA[2], eA[3]);
          uB.h[0] = __builtin_amdgcn_cvt_pkrtz(eB[0], eB[1]);
          uB.h[1] = __builtin_amdgcn_cvt_pkrtz(eB[2], eB[3]);
          *(f16x4*)&sP[w][0][lr][kb] = uA.v;
          *(f16x4*)&sP[w][1][lr][kb] = uB.v;
        }
      }
      m_run[0] = mA; m_run[1] = mB;
    }

    // ---- O += P V^T ; l += P * ones (both MFMA, all operands from LDS)
    __builtin_amdgcn_s_setprio(1);
#pragma unroll
    for (int s8g = 0; s8g < 2; s8g++){
      f16x8 pfA = as_f16x8(*(const uint4*)&sP[w][0][lr][s8g*32 + quad*8]);
      f16x8 pfB = as_f16x8(*(const uint4*)&sP[w][1][lr][s8g*32 + quad*8]);
      acc_l[0] = MFMA16(pfA, ones, acc_l[0]);
      acc_l[1] = MFMA16(pfB, ones, acc_l[1]);
      const int sx = ((s8g*4 + quad) ^ xr)*8;            // swizzled key-slot offset
#pragma unroll
      for (int nt = 0; nt < 4; nt++){
        f16x8 vf = as_f16x8(*(const uint4*)(sVc + (nt*16 + lr)*64 + sx));
        o[0][nt] = MFMA16(pfA, vf, o[0][nt]);
        o[1][nt] = MFMA16(pfB, vf, o[1][nt]);
      }
    }
    __builtin_amdgcn_s_setprio(0);
    SCHED_FENCE();
    __builtin_amdgcn_s_barrier();                        // all waves done with buf[cur]
    SCHED_FENCE();
  }

  // ---- epilogue: out = (O + eps/N * E * Vsum) / (l + eps * E)
#pragma unroll
  for (int tq = 0; tq < 2; tq++){
    float mq = m_run[tq];
    mq = fmaxf(mq, __shfl_xor(mq, 16));
    mq = fmaxf(mq, __shfl_xor(mq, 32));   // per-query (lr) global max, all lanes
#pragma unroll
    for (int i = 0; i < 4; i++){
      float mi = __shfl(mq, quad*4 + i);  // max for query row quad*4+i
      float E  = EXP2(mi);
      float li = acc_l[tq][i];            // row-sum for this query
      float inv = 1.0f / (li + 1e-6f*E);
      float ec  = (1e-6f/1024.0f)*E;
      int row = q0 + tq*16 + quad*4 + i;
      f16* op = O + (size_t)(b*NN + row)*NC + h*HD;
#pragma unroll
      for (int nt = 0; nt < 4; nt++)
        op[nt*16 + lr] = (f16)((o[tq][nt][i] + ec*vs[nt]) * inv);
    }
  }
}

// ---------------- proj GEMM: [16384,768] x [768,768]^T + bias -> fp32, 256x256 ----------------
__launch_bounds__(512, 2)
__global__ void gemm_proj(const f16* __restrict__ A, const f16* __restrict__ W,
                          const float* __restrict__ bias, float* __restrict__ out){
  __shared__ f16 sA[2*16384];
  __shared__ f16 sB[2*16384];
  GEMM256_PREAMBLE(3, 192);
  GEMM256_PIPELINE(A, W, sA, sB);
#pragma unroll
  for (int nt = 0; nt < 4; nt++){
    int colg = C0 + wc*64 + nt*16 + lr;
    float bv = bias[colg];
#pragma unroll
    for (int mt = 0; mt < 8; mt++)
#pragma unroll
      for (int i = 0; i < 4; i++){
        int row = R0 + wr*128 + mt*16 + quad*4 + i;
        out[(size_t)row*NC + colg] = acc[mt][nt][i] + bv;
      }
  }
}

extern "C" void kernel_launch(void* const* d_in, const int* in_sizes, int n_in,
                              void* d_out, int out_size, void* d_ws, size_t ws_size,
                              hipStream_t stream) {
  const float* x      = (const float*)d_in[0];
  const float* policy = (const float*)d_in[1];
  const float* w_qkv  = (const float*)d_in[2];
  const float* w_proj = (const float*)d_in[3];
  const float* b_proj = (const float*)d_in[4];
  float* out = (float*)d_out;

  f16* x_h     = (f16*)d_ws;
  f16* wqkv_h  = x_h + (size_t)NM*NC;
  f16* wproj_h = wqkv_h + (size_t)QKVC*NC;
  f16* q_h     = wproj_h + (size_t)NC*NC;
  f16* k_h     = q_h + (size_t)NM*NC;
  f16* vt_h    = k_h + (size_t)NM*NC;
  float* vsum_f = (float*)(vt_h + (size_t)NM*NC);
  f16* attn_h  = x_h;   // x dead after gemm_qkv -> reuse

  cvt_all<<<(CVT_N1+CVT_N2+CVT_N3)/256, 256, 0, stream>>>(x, w_qkv, w_proj, x_h, wqkv_h, wproj_h);

  gemm_qkv<<<dim3(QKVC/256, NM/256), 512, 0, stream>>>(x_h, wqkv_h, q_h, k_h, vt_h);

  vsum_kernel<<<dim3(NB*NH), 256, 0, stream>>>(vt_h, vsum_f);

  attn_kernel<<<dim3(NB*NH*(NN/128)), 256, 0, stream>>>(q_h, k_h, vt_h, policy, vsum_f, attn_h);

  gemm_proj<<<dim3(NC/256, NM/256), 512, 0, stream>>>(attn_h, wproj_h, b_proj, out);
}

// Round 11
// 313.888 us; speedup vs baseline: 1.1091x; 1.0214x over previous
//
#include <hip/hip_runtime.h>

// Attention with policy-softmax, MI355X (gfx950).
// Shapes: B=16, N=1024, C=768, H=12, hd=64.
// R16: proj reverted to the R11-verified 128x128/BK=32 3-buffer depth-2
// pipeline (+ bijective XCD remap). R12's 256^2 proj strands 64 CUs (192
// blocks, 1/CU) and cost ~+14us vs R10/R11's 768-block 3/CU single round.
// qkv kept at R15 (256^2 4-phase + LDS-transpose VT epilogue, 98us, WRITE
// 113->95MB). attn kept at R9b. cvt/vsum unchanged.

#define NB 16
#define NN 1024
#define NC 768
#define NH 12
#define HD 64
#define NM (NB*NN)      // 16384
#define QKVC (3*NC)     // 2304
#define QSCALE 0.18033688011112042f   // 0.125 * log2(e)
#define PSTR 68         // attn sP row stride in f16 (136B)
#define TSTR 264        // transpose-LDS row stride in f16 (528B, 16B-aligned)

typedef _Float16 f16;
typedef _Float16 f16x8 __attribute__((ext_vector_type(8)));
typedef _Float16 f16x4 __attribute__((ext_vector_type(4)));
typedef _Float16 f16x2 __attribute__((ext_vector_type(2)));
typedef __fp16 fp16x2 __attribute__((ext_vector_type(2)));   // cvt_pkrtz native type
typedef float f32x4 __attribute__((ext_vector_type(4)));

#if __has_builtin(__builtin_amdgcn_exp2f)
#define EXP2(x) __builtin_amdgcn_exp2f(x)
#else
#define EXP2(x) exp2f(x)
#endif

#define MFMA16(a,b,c) __builtin_amdgcn_mfma_f32_16x16x32_f16((a),(b),(c),0,0,0)
#define SCHED_FENCE() __builtin_amdgcn_sched_barrier(0)

__device__ inline f16x8 as_f16x8(uint4 u){
  union { uint4 u; f16x8 h; } v; v.u = u; return v.h;
}

// async global->LDS, 16B per lane; lds ptr must be wave-uniform (lane l lands at +l*16B)
__device__ inline void gl_lds16(const f16* g, f16* l){
  __builtin_amdgcn_global_load_lds(
      (const __attribute__((address_space(1))) void*)g,
      (__attribute__((address_space(3))) void*)l, 16, 0, 0);
}

// ---------------- fp32 -> f16 convert (all three tensors, one launch) ----------------
#define CVT_N1 (NM*NC/4)      // 3145728
#define CVT_N2 (QKVC*NC/4)    // 442368
#define CVT_N3 (NC*NC/4)      // 147456
__global__ void cvt_all(const float* __restrict__ x, const float* __restrict__ wq,
                        const float* __restrict__ wp, f16* __restrict__ xh,
                        f16* __restrict__ wqh, f16* __restrict__ wph){
  int i = blockIdx.x*blockDim.x + threadIdx.x;
  const float* in; f16* out; int j;
  if (i < CVT_N1){ in = x; out = xh; j = i; }
  else if (i < CVT_N1 + CVT_N2){ in = wq; out = wqh; j = i - CVT_N1; }
  else { in = wp; out = wph; j = i - CVT_N1 - CVT_N2; }
  float4 v = ((const float4*)in)[j];
  f16x4 h; h[0]=(f16)v.x; h[1]=(f16)v.y; h[2]=(f16)v.z; h[3]=(f16)v.w;
  ((f16x4*)out)[j] = h;
}

// ---------------- 256x256 / BK=64 GEMM, 4-phase/K-tile schedule (qkv) ----------------
#define G_STAGE1(SRC, DSTB, KT, RC0, J)                                       \
  gl_lds16(SRC + (size_t)((RC0) + (J)*64 + (t >> 3))*NC + (KT) + sslot*8,     \
           (DSTB) + (J)*4096 + wv*512);

#define G_STAGE4(SRC, DSTB, KT, RC0)                                          \
  { G_STAGE1(SRC, DSTB, KT, RC0, 0) G_STAGE1(SRC, DSTB, KT, RC0, 1)           \
    G_STAGE1(SRC, DSTB, KT, RC0, 2) G_STAGE1(SRC, DSTB, KT, RC0, 3) }

#define PH_READ_BF(KX)                                                        \
  _Pragma("unroll")                                                           \
  for (int nt = 0; nt < 4; nt++)                                              \
    bf[nt] = as_f16x8(*(const uint4*)(B_ + (wc*64 + nt*16 + lr)*64 + (KX)));

#define PH_READ_AF(M0, KX)                                                    \
  _Pragma("unroll")                                                           \
  for (int mt = 0; mt < 4; mt++)                                              \
    af[mt] = as_f16x8(*(const uint4*)(A_ + (wr*128 + ((M0)+mt)*16 + lr)*64 + (KX)));

#define PH_MFMA(M0)                                                           \
  asm volatile("s_waitcnt lgkmcnt(0)" ::: "memory");                          \
  SCHED_FENCE();                                                              \
  __builtin_amdgcn_s_setprio(1);                                              \
  _Pragma("unroll")                                                           \
  for (int mt = 0; mt < 4; mt++)                                              \
    _Pragma("unroll")                                                         \
    for (int nt = 0; nt < 4; nt++)                                            \
      acc[(M0)+mt][nt] = MFMA16(af[mt], bf[nt], acc[(M0)+mt][nt]);            \
  __builtin_amdgcn_s_setprio(0);                                              \
  SCHED_FENCE();

#define GEMM256_PIPELINE(SRC_A, SRC_B, SA, SB)                                \
  G_STAGE4(SRC_A, (SA), 0, R0);                                               \
  G_STAGE4(SRC_B, (SB), 0, C0);                                               \
  _Pragma("unroll 1")                                                         \
  for (int tt = 0; tt < 12; tt++){                                            \
    const int cur = tt & 1;                                                   \
    const int kn = (tt + 1)*64;                                               \
    const bool st = (tt < 11);                                                \
    asm volatile("s_waitcnt vmcnt(0)" ::: "memory");   /* own tile-old DMA */ \
    SCHED_FENCE();                                                            \
    __builtin_amdgcn_s_barrier();                      /* buf[cur] ready   */ \
    SCHED_FENCE();                                                            \
    const f16* A_ = (SA) + (cur ? 16384 : 0);                                 \
    const f16* B_ = (SB) + (cur ? 16384 : 0);                                 \
    f16* An_ = (SA) + (cur ? 0 : 16384);                                      \
    f16* Bn_ = (SB) + (cur ? 0 : 16384);                                      \
    f16x8 af[4], bf[4];                                                       \
    /* phase 0: khalf0, acc[0..3] */                                          \
    PH_READ_BF(kxA0); PH_READ_AF(0, kxA0);                                    \
    SCHED_FENCE();                                                            \
    if (st){ G_STAGE1(SRC_A, An_, kn, R0, 0) G_STAGE1(SRC_A, An_, kn, R0, 1) }\
    SCHED_FENCE();                                                            \
    __builtin_amdgcn_s_barrier();                                             \
    PH_MFMA(0);                                                               \
    __builtin_amdgcn_s_barrier();                                             \
    SCHED_FENCE();                                                            \
    /* phase 1: khalf0, acc[4..7] */                                          \
    PH_READ_AF(4, kxA0);                                                      \
    SCHED_FENCE();                                                            \
    if (st){ G_STAGE1(SRC_A, An_, kn, R0, 2) G_STAGE1(SRC_A, An_, kn, R0, 3) }\
    SCHED_FENCE();                                                            \
    __builtin_amdgcn_s_barrier();                                             \
    PH_MFMA(4);                                                               \
    __builtin_amdgcn_s_barrier();                                             \
    SCHED_FENCE();                                                            \
    /* phase 2: khalf1, acc[0..3] */                                          \
    PH_READ_BF(kxA1); PH_READ_AF(0, kxA1);                                    \
    SCHED_FENCE();                                                            \
    if (st){ G_STAGE1(SRC_B, Bn_, kn, C0, 0) G_STAGE1(SRC_B, Bn_, kn, C0, 1) }\
    SCHED_FENCE();                                                            \
    __builtin_amdgcn_s_barrier();                                             \
    PH_MFMA(0);                                                               \
    __builtin_amdgcn_s_barrier();                                             \
    SCHED_FENCE();                                                            \
    /* phase 3: khalf1, acc[4..7] */                                          \
    PH_READ_AF(4, kxA1);                                                      \
    SCHED_FENCE();                                                            \
    if (st){ G_STAGE1(SRC_B, Bn_, kn, C0, 2) G_STAGE1(SRC_B, Bn_, kn, C0, 3) }\
    SCHED_FENCE();                                                            \
    __builtin_amdgcn_s_barrier();                                             \
    PH_MFMA(4);                                                               \
    __builtin_amdgcn_s_barrier();                                             \
    SCHED_FENCE();                                                            \
  }

// Bijective XCD remap (grid % 8 == 0), x-fastest decompose.
#define GEMM256_PREAMBLE(NBX, NWG)                                           \
  const int flat_ = blockIdx.y*(NBX) + blockIdx.x;                            \
  const int wg_ = (flat_ % 8)*((NWG)/8) + flat_/8;                            \
  const int R0 = (wg_/(NBX))*256, C0 = (wg_%(NBX))*256;                       \
  const int t = threadIdx.x;                                                  \
  const int wv = t >> 6, l = t & 63, quad = l >> 4, lr = l & 15;              \
  const int wr = wv >> 2, wc = wv & 3;                                        \
  const int sslot = (t & 7) ^ ((t >> 3) & 7);                                 \
  const int xr = lr & 7;                                                      \
  const int kxA0 = (quad ^ xr)*8;                                             \
  const int kxA1 = ((4 + quad) ^ xr)*8;                                       \
  f32x4 acc[8][4] = {};

// ---------------- QKV GEMM: [16384,768] x [2304,768]^T, 256x256 tile ----------------
__launch_bounds__(512, 2)
__global__ void gemm_qkv(const f16* __restrict__ X, const f16* __restrict__ W,
                         f16* __restrict__ Q, f16* __restrict__ K, f16* __restrict__ VT){
  __shared__ __align__(16) f16 smem[256*TSTR];   // 135168 B
  f16* const sAp = smem;                          // 2 x 16384 f16
  f16* const sBp = smem + 32768;                  // 2 x 16384 f16
  GEMM256_PREAMBLE(9, 576);
  GEMM256_PIPELINE(X, W, sAp, sBp);
  // scatter into Q / K / V^T. type uniform per block (256 | 768, 768=3*256).
  const int type = C0 / NC;
  if (type != 2){
#pragma unroll
    for (int nt = 0; nt < 4; nt++){
      int colg = C0 + wc*64 + nt*16 + lr;
      int rem  = colg - type*NC;
      int hh = rem >> 6, d = rem & 63;
#pragma unroll
      for (int mt = 0; mt < 8; mt++)
#pragma unroll
        for (int i = 0; i < 4; i++){
          int row = R0 + wr*128 + mt*16 + quad*4 + i;
          int bb = row >> 10, np = row & 1023;
          int bh = bb*NH + hh;
          float a = acc[mt][nt][i];
          if (type == 0) Q[(bh << 16) + (np << 6) + d] = (f16)(a * QSCALE);
          else           K[(bh << 16) + (np << 6) + d] = (f16)a;
        }
    }
  } else {
    // ---- V: transpose 256x256 tile through LDS, store coalesced to VT ----
    f16* const sT = smem;      // [col 0..255][TSTR]
#pragma unroll
    for (int nt = 0; nt < 4; nt++){
      const int col = wc*64 + nt*16 + lr;          // local d-col 0..255
#pragma unroll
      for (int mt = 0; mt < 8; mt++){
        const int npl = wr*128 + mt*16 + quad*4;   // local row 0..255 (4 consec)
        f16x2 h0; h0[0] = (f16)acc[mt][nt][0]; h0[1] = (f16)acc[mt][nt][1];
        f16x2 h1; h1[0] = (f16)acc[mt][nt][2]; h1[1] = (f16)acc[mt][nt][3];
        *(f16x2*)&sT[col*TSTR + npl]     = h0;
        *(f16x2*)&sT[col*TSTR + npl + 2] = h1;
      }
    }
    __syncthreads();
    const int c    = t >> 1;                        // local d-col 0..255
    const int half = t & 1;                         // np half 0/1
    const int cg   = (C0 - 2*NC) + c;               // global V column 0..767
    const int bb   = R0 >> 10;                      // same b for whole block
    const int np0  = (R0 & 1023) + half*128;
    const int hh   = cg >> 6, d = cg & 63;
    const int bh   = bb*NH + hh;
    f16* dst = VT + ((size_t)bh << 16) + (d << 10) + np0;
    const f16* srcl = sT + c*TSTR + half*128;
#pragma unroll
    for (int j = 0; j < 16; j++)
      *(uint4*)(dst + j*8) = *(const uint4*)(srcl + j*8);
  }
}

// ---------------- Vsum: column sums of V per (b,h) ----------------
__global__ void vsum_kernel(const f16* __restrict__ VT, float* __restrict__ vsum){
  int bh = blockIdx.x;
  int t = threadIdx.x;
  int row = t >> 2, part = t & 3;
  const uint4* p = (const uint4*)(VT + ((size_t)bh << 16) + row*NN + part*256);
  float s = 0.f;
#pragma unroll
  for (int i = 0; i < 32; i++){
    f16x8 v = as_f16x8(p[i]);
#pragma unroll
    for (int j = 0; j < 8; j++) s += (float)v[j];
  }
  __shared__ float sR[64][4];
  sR[row][part] = s;
  __syncthreads();
  if (t < 64) vsum[bh*64 + t] = sR[t][0] + sR[t][1] + sR[t][2] + sR[t][3];
}

// ---------------- fused policy-softmax attention (no-max-subtract) ----------------
// (unchanged from R9b — DMA pipeline, verified)
#define STAGE(BUF, KEY0H)                                                     \
  _Pragma("unroll")                                                           \
  for (int j = 0; j < 2; j++){                                                \
    const int s_  = j*256 + t;                                                \
    const int r_  = s_ >> 3;                                                  \
    const int sl_ = (s_ & 7) ^ (r_ & 7);                                      \
    f16* du_ = (f16*)&sK[BUF][(j*256 + (t & 192))*8];                         \
    f16* dv_ = (f16*)&sVT[BUF][(j*256 + (t & 192))*8];                        \
    gl_lds16(Kg  + (size_t)((KEY0H) + r_)*HD + sl_*8, du_);                   \
    gl_lds16(VTg + (size_t)r_*NN + (KEY0H) + sl_*8,   dv_);                   \
  }

__launch_bounds__(256, 3)
__global__ void attn_kernel(const f16* __restrict__ Q, const f16* __restrict__ K,
                            const f16* __restrict__ VT, const float* __restrict__ policy,
                            const float* __restrict__ vsum, f16* __restrict__ O){
  __shared__ f16 sK[2][4096];          // 16 KB: 64 keys x 64 d, swizzled
  __shared__ f16 sVT[2][4096];         // 16 KB: 64 d x 64 keys, swizzled
  __shared__ f16 sP[4][2][16][PSTR];   // 17408 B
  __shared__ float sPol[1024];         // 4096 B  -> total 54272 B, 3 blocks/CU

  const int blk = blockIdx.x;
  const int bh = blk % (NB*NH);
  const int qt = blk / (NB*NH);
  const int b = bh / NH;
  const size_t base = (size_t)bh << 16;

  const int t = threadIdx.x;
  const int w = t >> 6, l = t & 63, quad = l >> 4, lr = l & 15;
  const int q0 = qt*128 + w*32;
  const int qrow = q0 + lr;
  const int h = bh - b*NH;
  const int xr = lr & 7;                       // row&7 for all tile rows (16-aligned)
  const int kx0 = (quad ^ xr)*8;               // swizzled f16 offset, d 0..31 slot
  const int kx1 = ((4 + quad) ^ xr)*8;         // d 32..63 slot

  *(float4*)&sPol[t*4] = *(const float4*)(policy + b*NN + t*4);

  // Q fragments (pre-scaled), contiguous 16B global reads
  f16x8 qf[2][2];
#pragma unroll
  for (int tq = 0; tq < 2; tq++)
#pragma unroll
    for (int hf = 0; hf < 2; hf++)
      qf[tq][hf] = as_f16x8(*(const uint4*)(Q + base + (size_t)(q0 + tq*16 + lr)*HD + hf*32 + quad*8));

  float vs[4];
#pragma unroll
  for (int nt = 0; nt < 4; nt++) vs[nt] = vsum[bh*64 + nt*16 + lr];

  f16x8 ones;
#pragma unroll
  for (int j = 0; j < 8; j++) ones[j] = (f16)1.0f;

  float m_run[2] = {-INFINITY, -INFINITY};
  f32x4 acc_l[2] = {};
  f32x4 o[2][4] = {};

  const f16* Kg  = K + base;
  const f16* VTg = VT + base;

  // prologue: stage step 0, drain everything (incl. qf/vs vmem + sPol lds)
  STAGE(0, 0);
  asm volatile("s_waitcnt vmcnt(0) lgkmcnt(0)" ::: "memory");
  SCHED_FENCE();
  __builtin_amdgcn_s_barrier();
  SCHED_FENCE();

#pragma unroll 1
  for (int hs = 0; hs < 16; hs++){
    const int cur = hs & 1;
    const int key0h = hs*64;
    if (hs < 15){
      STAGE(cur^1, key0h + 64);
      asm volatile("s_waitcnt vmcnt(4)" ::: "memory");   // drain prev stage, keep 4 in flight
    } else {
      asm volatile("s_waitcnt vmcnt(0)" ::: "memory");
    }
    SCHED_FENCE();
    __builtin_amdgcn_s_barrier();                        // buf[cur] fully staged (all waves)
    SCHED_FENCE();

    const f16* sKc = (const f16*)sK[cur];
    const f16* sVc = (const f16*)sVT[cur];

    // ---- S^T = K · Q^T for 64 keys (rows) x 32 queries
    f32x4 accA[4], accB[4];
#pragma unroll
    for (int ct = 0; ct < 4; ct++){ accA[ct] = (f32x4){0,0,0,0}; accB[ct] = (f32x4){0,0,0,0}; }
    __builtin_amdgcn_s_setprio(1);
#pragma unroll
    for (int ct = 0; ct < 4; ct++){
      const f16* kp = sKc + (ct*16 + lr)*64;
      f16x8 k0 = as_f16x8(*(const uint4*)(kp + kx0));
      f16x8 k1 = as_f16x8(*(const uint4*)(kp + kx1));
      accA[ct] = MFMA16(k0, qf[0][0], accA[ct]);
      accA[ct] = MFMA16(k1, qf[0][1], accA[ct]);
      accB[ct] = MFMA16(k0, qf[1][0], accB[ct]);
      accB[ct] = MFMA16(k1, qf[1][1], accB[ct]);
    }
    __builtin_amdgcn_s_setprio(0);

    // ---- softmax * policy -> sP (per-wave tile), running max
    {
      float mA = m_run[0], mB = m_run[1];
      const bool diag = (hs == 2*qt + (w >> 1));         // wave-uniform
      if (!diag){
#pragma unroll
        for (int ct = 0; ct < 4; ct++){
          const int kb = ct*16 + quad*4;
          float4 pol4 = *(const float4*)&sPol[key0h + kb];
          const float* p4 = (const float*)&pol4;
          mA = fmaxf(mA, fmaxf(fmaxf(accA[ct][0], accA[ct][1]), fmaxf(accA[ct][2], accA[ct][3])));
          mB = fmaxf(mB, fmaxf(fmaxf(accB[ct][0], accB[ct][1]), fmaxf(accB[ct][2], accB[ct][3])));
          union { f16x4 v; fp16x2 h[2]; } uA, uB;
          uA.h[0] = __builtin_amdgcn_cvt_pkrtz(EXP2(accA[ct][0])*p4[0], EXP2(accA[ct][1])*p4[1]);
          uA.h[1] = __builtin_amdgcn_cvt_pkrtz(EXP2(accA[ct][2])*p4[2], EXP2(accA[ct][3])*p4[3]);
          uB.h[0] = __builtin_amdgcn_cvt_pkrtz(EXP2(accB[ct][0])*p4[0], EXP2(accB[ct][1])*p4[1]);
          uB.h[1] = __builtin_amdgcn_cvt_pkrtz(EXP2(accB[ct][2])*p4[2], EXP2(accB[ct][3])*p4[3]);
          *(f16x4*)&sP[w][0][lr][kb] = uA.v;
          *(f16x4*)&sP[w][1][lr][kb] = uB.v;
        }
      } else {
#pragma unroll
        for (int ct = 0; ct < 4; ct++){
          const int kb = ct*16 + quad*4;
          float4 pol4 = *(const float4*)&sPol[key0h + kb];
          const float* p4 = (const float*)&pol4;
          float eA[4], eB[4];
#pragma unroll
          for (int i2 = 0; i2 < 4; i2++){
            int kg = key0h + kb + i2;
            float polA = (kg == qrow)      ? 1.0f : p4[i2];
            float polB = (kg == qrow + 16) ? 1.0f : p4[i2];
            mA = fmaxf(mA, accA[ct][i2]); mB = fmaxf(mB, accB[ct][i2]);
            eA[i2] = EXP2(accA[ct][i2]) * polA;
            eB[i2] = EXP2(accB[ct][i2]) * polB;
          }
          union { f16x4 v; fp16x2 h[2]; } uA, uB;
          uA.h[0] = __builtin_amdgcn_cvt_pkrtz(eA[0], eA[1]);
          uA.h[1] = __builtin_amdgcn_cvt_pkrtz(eA[2], eA[3]);
          uB.h[0] = __builtin_amdgcn_cvt_pkrtz(eB[0], eB[1]);
          uB.h[1] = __builtin_amdgcn_cvt_pkrtz(eB[2], eB[3]);
          *(f16x4*)&sP[w][0][lr][kb] = uA.v;
          *(f16x4*)&sP[w][1][lr][kb] = uB.v;
        }
      }
      m_run[0] = mA; m_run[1] = mB;
    }

    // ---- O += P V^T ; l += P * ones (both MFMA, all operands from LDS)
    __builtin_amdgcn_s_setprio(1);
#pragma unroll
    for (int s8g = 0; s8g < 2; s8g++){
      f16x8 pfA = as_f16x8(*(const uint4*)&sP[w][0][lr][s8g*32 + quad*8]);
      f16x8 pfB = as_f16x8(*(const uint4*)&sP[w][1][lr][s8g*32 + quad*8]);
      acc_l[0] = MFMA16(pfA, ones, acc_l[0]);
      acc_l[1] = MFMA16(pfB, ones, acc_l[1]);
      const int sx = ((s8g*4 + quad) ^ xr)*8;            // swizzled key-slot offset
#pragma unroll
      for (int nt = 0; nt < 4; nt++){
        f16x8 vf = as_f16x8(*(const uint4*)(sVc + (nt*16 + lr)*64 + sx));
        o[0][nt] = MFMA16(pfA, vf, o[0][nt]);
        o[1][nt] = MFMA16(pfB, vf, o[1][nt]);
      }
    }
    __builtin_amdgcn_s_setprio(0);
    SCHED_FENCE();
    __builtin_amdgcn_s_barrier();                        // all waves done with buf[cur]
    SCHED_FENCE();
  }

  // ---- epilogue: out = (O + eps/N * E * Vsum) / (l + eps * E)
#pragma unroll
  for (int tq = 0; tq < 2; tq++){
    float mq = m_run[tq];
    mq = fmaxf(mq, __shfl_xor(mq, 16));
    mq = fmaxf(mq, __shfl_xor(mq, 32));   // per-query (lr) global max, all lanes
#pragma unroll
    for (int i = 0; i < 4; i++){
      float mi = __shfl(mq, quad*4 + i);  // max for query row quad*4+i
      float E  = EXP2(mi);
      float li = acc_l[tq][i];            // row-sum for this query
      float inv = 1.0f / (li + 1e-6f*E);
      float ec  = (1e-6f/1024.0f)*E;
      int row = q0 + tq*16 + quad*4 + i;
      f16* op = O + (size_t)(b*NN + row)*NC + h*HD;
#pragma unroll
      for (int nt = 0; nt < 4; nt++)
        op[nt*16 + lr] = (f16)((o[tq][nt][i] + ec*vs[nt]) * inv);
    }
  }
}

// ---------------- proj GEMM: 128x128 / BK=32, 3-buffer depth-2 (R11-verified) ----------------
#define P_STAGE(SRC_A, SRC_B, BUF, BK)                                        \
  _Pragma("unroll")                                                           \
  for (int r = 0; r < 2; r++){                                                \
    int row = r*64 + row0;                                                    \
    gl_lds16(SRC_A + (size_t)(R0 + row)*NC + (BK) + kc0, sA[BUF] + r*2048 + w*512); \
    gl_lds16(SRC_B + (size_t)(C0 + row)*NC + (BK) + kc0, sB[BUF] + r*2048 + w*512); \
  }

__launch_bounds__(256)
__global__ void gemm_proj(const f16* __restrict__ A, const f16* __restrict__ W,
                          const float* __restrict__ bias, float* __restrict__ out){
  __shared__ f16 sA[3][128*32];   // 3 x 8 KB
  __shared__ f16 sB[3][128*32];
  // bijective XCD remap on 768-block grid (768 % 8 == 0), x-fastest
  const int flat = blockIdx.y*6 + blockIdx.x;
  const int wg = (flat % 8)*96 + flat/8;
  const int R0 = (wg/6)*128, C0 = (wg%6)*128;
  const int t = threadIdx.x;
  const int w = t >> 6, l = t & 63, quad = l >> 4, lr = l & 15;
  const int wr = w >> 1, wc = w & 1;
  const int row0 = t >> 2, kc0 = (t & 3)*8;
  f32x4 acc[4][4] = {};
  P_STAGE(A, W, 0, 0);
  P_STAGE(A, W, 1, 32);
#pragma unroll 1
  for (int kt = 0; kt < 24; kt++){
    const int cur = kt % 3;
    if (kt < 22){
      P_STAGE(A, W, (kt+2) % 3, (kt+2)*32);
      asm volatile("s_waitcnt vmcnt(8)" ::: "memory");
    } else if (kt == 22){
      asm volatile("s_waitcnt vmcnt(4)" ::: "memory");
    } else {
      asm volatile("s_waitcnt vmcnt(0)" ::: "memory");
    }
    SCHED_FENCE();
    __builtin_amdgcn_s_barrier();
    SCHED_FENCE();
    f16x8 af[4], bf[4];
#pragma unroll
    for (int mt = 0; mt < 4; mt++)
      af[mt] = as_f16x8(*(const uint4*)(sA[cur] + (wr*64 + mt*16 + lr)*32 + quad*8));
#pragma unroll
    for (int nt = 0; nt < 4; nt++)
      bf[nt] = as_f16x8(*(const uint4*)(sB[cur] + (wc*64 + nt*16 + lr)*32 + quad*8));
    __builtin_amdgcn_s_setprio(1);
#pragma unroll
    for (int mt = 0; mt < 4; mt++)
#pragma unroll
      for (int nt = 0; nt < 4; nt++)
        acc[mt][nt] = MFMA16(af[mt], bf[nt], acc[mt][nt]);
    __builtin_amdgcn_s_setprio(0);
    SCHED_FENCE();
    __builtin_amdgcn_s_barrier();
    SCHED_FENCE();
  }
#pragma unroll
  for (int nt = 0; nt < 4; nt++){
    int colg = C0 + wc*64 + nt*16 + lr;
    float bv = bias[colg];
#pragma unroll
    for (int mt = 0; mt < 4; mt++)
#pragma unroll
      for (int i = 0; i < 4; i++){
        int row = R0 + wr*64 + mt*16 + quad*4 + i;
        out[(size_t)row*NC + colg] = acc[mt][nt][i] + bv;
      }
  }
}

extern "C" void kernel_launch(void* const* d_in, const int* in_sizes, int n_in,
                              void* d_out, int out_size, void* d_ws, size_t ws_size,
                              hipStream_t stream) {
  const float* x      = (const float*)d_in[0];
  const float* policy = (const float*)d_in[1];
  const float* w_qkv  = (const float*)d_in[2];
  const float* w_proj = (const float*)d_in[3];
  const float* b_proj = (const float*)d_in[4];
  float* out = (float*)d_out;

  f16* x_h     = (f16*)d_ws;
  f16* wqkv_h  = x_h + (size_t)NM*NC;
  f16* wproj_h = wqkv_h + (size_t)QKVC*NC;
  f16* q_h     = wproj_h + (size_t)NC*NC;
  f16* k_h     = q_h + (size_t)NM*NC;
  f16* vt_h    = k_h + (size_t)NM*NC;
  float* vsum_f = (float*)(vt_h + (size_t)NM*NC);
  f16* attn_h  = x_h;   // x dead after gemm_qkv -> reuse

  cvt_all<<<(CVT_N1+CVT_N2+CVT_N3)/256, 256, 0, stream>>>(x, w_qkv, w_proj, x_h, wqkv_h, wproj_h);

  gemm_qkv<<<dim3(QKVC/256, NM/256), 512, 0, stream>>>(x_h, wqkv_h, q_h, k_h, vt_h);

  vsum_kernel<<<dim3(NB*NH), 256, 0, stream>>>(vt_h, vsum_f);

  attn_kernel<<<dim3(NB*NH*(NN/128)), 256, 0, stream>>>(q_h, k_h, vt_h, policy, vsum_f, attn_h);

  gemm_proj<<<dim3(NC/128, NM/128), 256, 0, stream>>>(attn_h, wproj_h, b_proj, out);
}